// Round 4
// baseline (303.763 us; speedup 1.0000x reference)
//
#include <hip/hip_runtime.h>
#include <hip/hip_bf16.h>

#define NB 2
#define NN 8192
#define NC 256
#define NH 8
#define NCH 2048

static constexpr float EPS = 1e-5f;

// ---------------------------------------------------------------------------
// Factorization (per batch b, head h):
//   G = emb^T emb                         [256x256] (tri tiles, split-K)
//   attn_h = (Wq_h^T G) Wk_h              (fused in k_qksm, chunked via LDS)
//   SM = softmax(attn * rsqrt(var+eps))   (in-register, mean shift cancels)
//   M = Wv_h SM^T ; Pt_h = Wor_h M^T      (fused in k_ctx)
//   out = emb @ Pt^T,  Pt = sum_h Pt_h
// All GEMM operands bf16 hi/lo pairs: x = hi + lo; acc += hi*hi + hi*lo + lo*hi.
// ---------------------------------------------------------------------------

typedef __attribute__((ext_vector_type(8))) short bf16x8;
typedef __attribute__((ext_vector_type(4))) float f32x4;

#define MFMA16(a, b, c) __builtin_amdgcn_mfma_f32_16x16x32_bf16(a, b, c, 0, 0, 0)

// ---- ws layout -------------------------------------------------------------
// float region:
//   Gp  [2][16][10][4096] @ 0        (1,310,720)
//   Ptp [16][256][256]    @ 1310720  (1,048,576)
// ushort region at float offset 2359296:
static constexpr int ETH  = 0;         // Et hi [2][256][8192]
static constexpr int ETL  = 4194304;
static constexpr int WQTH = 8388608;   // Wq^T hi [2048][256]
static constexpr int WQTL = 8912896;
static constexpr int WKTH = 9437184;
static constexpr int WKTL = 9961472;
static constexpr int WVH  = 10485760;  // Wv hi [256][2048]
static constexpr int WVL  = 11010048;
static constexpr int WORH = 11534336;  // Wor hi [8][256][256]: Wor[h][j][d] = Wo[d*8+h][j]
static constexpr int WORL = 12058624;
static constexpr int GHH  = 12582912;  // G hi [2][256][256]
static constexpr int GHL  = 12713984;
static constexpr int SMH  = 12845056;  // softmax hi [16][256][256]
static constexpr int SML  = 13893632;
static constexpr int PTH  = 14942208;  // Pt hi [2][256][256]
static constexpr int PTL  = 15073280;

// ---- helpers ---------------------------------------------------------------

__device__ __forceinline__ ushort bf16rn(float x) {
    uint u = __float_as_uint(x);
    return (ushort)((u + 0x7fffu + ((u >> 16) & 1u)) >> 16);
}
__device__ __forceinline__ float bf2f(ushort h) { return __uint_as_float(((uint)h) << 16); }

// stage 64x64 bf16 tile (k-contiguous source) into XOR-swizzled LDS (256 thr).
__device__ __forceinline__ void stage64(ushort* __restrict__ lds, const ushort* __restrict__ src,
                                        int row0, int k0, int ld) {
    int t = threadIdx.x;
    int g = t & 7, r = t >> 3;
#pragma unroll
    for (int i = 0; i < 2; ++i, r += 32) {
        uint4 v = *(const uint4*)(src + (row0 + r) * ld + k0 + g * 8);
        *(uint4*)((char*)lds + r * 128 + ((g ^ (r & 7)) << 4)) = v;
    }
}

// same, 512 threads, NR rows
template <int NR>
__device__ __forceinline__ void stg(ushort* __restrict__ lds, const ushort* __restrict__ src,
                                    int row0, int k0, int ld) {
    int t = threadIdx.x;
    int g = t & 7, r = t >> 3;  // rows 0..63 per pass
#pragma unroll
    for (int i = 0; i < NR / 64; ++i) {
        int rr = r + i * 64;
        uint4 v = *(const uint4*)(src + (row0 + rr) * ld + k0 + g * 8);
        *(uint4*)((char*)lds + rr * 128 + ((g ^ (rr & 7)) << 4)) = v;
    }
}

// stage 64x64 from fp32 source with on-the-fly hi/lo split (256 thr)
__device__ __forceinline__ void stage64_f32(ushort* __restrict__ ldsh, ushort* __restrict__ ldsl,
                                            const float* __restrict__ src, int row0, int k0, int ld) {
    int t = threadIdx.x;
    int g = t & 15, r = t >> 4;
#pragma unroll
    for (int i = 0; i < 4; ++i, r += 16) {
        float4 v = *(const float4*)(src + (row0 + r) * ld + k0 + g * 4);
        ushort h0 = bf16rn(v.x), h1 = bf16rn(v.y), h2 = bf16rn(v.z), h3 = bf16rn(v.w);
        ushort e0 = bf16rn(v.x - bf2f(h0)), e1 = bf16rn(v.y - bf2f(h1));
        ushort e2 = bf16rn(v.z - bf2f(h2)), e3 = bf16rn(v.w - bf2f(h3));
        int byte = r * 128 + ((((g >> 1) ^ (r & 7)) << 4) | ((g & 1) << 3));
        ushort4 hv = {h0, h1, h2, h3}, lv = {e0, e1, e2, e3};
        *(ushort4*)((char*)ldsh + byte) = hv;
        *(ushort4*)((char*)ldsl + byte) = lv;
    }
}

// read A/B fragment: lane row rbase+(l&15), 8 bf16 at k = ks*32+(l>>4)*8
__device__ __forceinline__ bf16x8 frag64(const ushort* __restrict__ lds, int rbase, int ks) {
    int l = threadIdx.x & 63;
    int r = rbase + (l & 15);
    int slot = (ks * 4 + (l >> 4)) ^ (r & 7);
    return *(const bf16x8*)((const char*)lds + r * 128 + slot * 16);
}

__device__ __forceinline__ void mac3(f32x4& acc, bf16x8 ah, bf16x8 al, bf16x8 bh, bf16x8 bl) {
    acc = MFMA16(ah, bh, acc);
    acc = MFMA16(ah, bl, acc);
    acc = MFMA16(al, bh, acc);
}

// 4-wave 64x64 mfma over one staged k-tile (256-thr kernels)
__device__ __forceinline__ void mfma_tile(const ushort* Ah, const ushort* Al,
                                          const ushort* Bh, const ushort* Bl,
                                          int wm, int wn, f32x4 acc[2][2]) {
#pragma unroll
    for (int ks = 0; ks < 2; ++ks) {
        bf16x8 ah[2], al[2], bh[2], bl[2];
        ah[0] = frag64(Ah, wm, ks);      ah[1] = frag64(Ah, wm + 16, ks);
        al[0] = frag64(Al, wm, ks);      al[1] = frag64(Al, wm + 16, ks);
        bh[0] = frag64(Bh, wn, ks);      bh[1] = frag64(Bh, wn + 16, ks);
        bl[0] = frag64(Bl, wn, ks);      bl[1] = frag64(Bl, wn + 16, ks);
#pragma unroll
        for (int mi = 0; mi < 2; ++mi)
#pragma unroll
            for (int ni = 0; ni < 2; ++ni)
                mac3(acc[mi][ni], ah[mi], al[mi], bh[ni], bl[ni]);
    }
}

__device__ __forceinline__ void ep_f32(float* D, int ld, int row0, int col0, f32x4 acc[2][2]) {
    int l = threadIdx.x & 63, w = threadIdx.x >> 6;
    int wm = (w >> 1) * 32, wn = (w & 1) * 32;
#pragma unroll
    for (int mi = 0; mi < 2; ++mi)
#pragma unroll
        for (int ni = 0; ni < 2; ++ni)
#pragma unroll
            for (int r = 0; r < 4; ++r)
                D[(row0 + wm + mi * 16 + (l >> 4) * 4 + r) * ld + col0 + wn + ni * 16 + (l & 15)] = acc[mi][ni][r];
}

// transpose+split a 64x64 fp32 tile: src[m*srcStride + j] -> dst[j*NC + m] (hi/lo)
__device__ __forceinline__ void tsplit(uint (*lds)[65], const float* __restrict__ src, int srcStride,
                                       ushort* __restrict__ DH, ushort* __restrict__ DL) {
    int t = threadIdx.x;
    int r = t >> 4, g = t & 15;
#pragma unroll
    for (int i = 0; i < 4; ++i) {
        int m = r + i * 16;
        float4 v = *(const float4*)(src + m * srcStride + g * 4);
        ushort h;
        h = bf16rn(v.x); lds[g * 4 + 0][m] = h | ((uint)bf16rn(v.x - bf2f(h)) << 16);
        h = bf16rn(v.y); lds[g * 4 + 1][m] = h | ((uint)bf16rn(v.y - bf2f(h)) << 16);
        h = bf16rn(v.z); lds[g * 4 + 2][m] = h | ((uint)bf16rn(v.z - bf2f(h)) << 16);
        h = bf16rn(v.w); lds[g * 4 + 3][m] = h | ((uint)bf16rn(v.w - bf2f(h)) << 16);
    }
    __syncthreads();
    int j = t >> 3, q = t & 7;
#pragma unroll
    for (int i = 0; i < 2; ++i) {
        int jj = j + i * 32;
        uint a0 = lds[jj][q * 8 + 0], a1 = lds[jj][q * 8 + 1], a2 = lds[jj][q * 8 + 2], a3 = lds[jj][q * 8 + 3];
        uint a4 = lds[jj][q * 8 + 4], a5 = lds[jj][q * 8 + 5], a6 = lds[jj][q * 8 + 6], a7 = lds[jj][q * 8 + 7];
        uint4 hv = {(a0 & 0xffffu) | (a1 << 16), (a2 & 0xffffu) | (a3 << 16),
                    (a4 & 0xffffu) | (a5 << 16), (a6 & 0xffffu) | (a7 << 16)};
        uint4 lv = {(a0 >> 16) | (a1 & 0xffff0000u), (a2 >> 16) | (a3 & 0xffff0000u),
                    (a4 >> 16) | (a5 & 0xffff0000u), (a6 >> 16) | (a7 & 0xffff0000u)};
        *(uint4*)(DH + jj * NC + q * 8) = hv;
        *(uint4*)(DL + jj * NC + q * 8) = lv;
    }
}

// ---- kernels ---------------------------------------------------------------

// weight prep: z=0 Wq^T, z=1 Wk^T, z=2 Wo rearrange, z=3 Wv split
__global__ __launch_bounds__(256) void k_prep(const float* __restrict__ wq, const float* __restrict__ wk,
                                              const float* __restrict__ wv, const float* __restrict__ wo,
                                              ushort* __restrict__ us) {
    __shared__ uint lds[64][65];
    int x = blockIdx.x, z = blockIdx.y;
    int t = threadIdx.x;
    if (z == 3) {
        int i = (x * 256 + t) * 4;
        float4 v = *(const float4*)(wv + i);
        ushort h0 = bf16rn(v.x), h1 = bf16rn(v.y), h2 = bf16rn(v.z), h3 = bf16rn(v.w);
        ushort e0 = bf16rn(v.x - bf2f(h0)), e1 = bf16rn(v.y - bf2f(h1));
        ushort e2 = bf16rn(v.z - bf2f(h2)), e3 = bf16rn(v.w - bf2f(h3));
        ushort4 hv = {h0, h1, h2, h3}, lv = {e0, e1, e2, e3};
        *(ushort4*)(us + WVH + i) = hv;
        *(ushort4*)(us + WVL + i) = lv;
        return;
    }
    if (x >= 128) return;
    if (z == 2) {
        int h = x >> 4, dt = (x >> 2) & 3, jt = x & 3;
        tsplit(lds, wo + (dt * 64 * 8 + h) * NC + jt * 64, 8 * NC,
               us + WORH + h * 65536 + (jt * 64) * NC + dt * 64,
               us + WORL + h * 65536 + (jt * 64) * NC + dt * 64);
        return;
    }
    int jt = x >> 2, ct = x & 3;
    const float* W = z ? wk : wq;
    int dh = (z ? WKTH : WQTH) + (jt * 64) * NC + ct * 64;
    int dl = (z ? WKTL : WQTL) + (jt * 64) * NC + ct * 64;
    tsplit(lds, W + (ct * 64) * NCH + jt * 64, NCH, us + dh, us + dl);
}

// emb -> Et hi/lo [b][c][n] (transpose + split). grid (128 nt, 4 ct, 2 b)
__global__ __launch_bounds__(256) void k_s0(const float* __restrict__ emb, ushort* __restrict__ us) {
    __shared__ uint lds[64][65];
    int nt = blockIdx.x, ct = blockIdx.y, b = blockIdx.z;
    int t = threadIdx.x;
    const float* E = emb + b * (NN * NC);
    int n0 = nt * 64, c0 = ct * 64;
    int r = t >> 4, g = t & 15;
#pragma unroll
    for (int i = 0; i < 4; ++i) {
        int n = r + i * 16;
        float4 v = *(const float4*)(E + (n0 + n) * NC + c0 + g * 4);
        ushort h;
        h = bf16rn(v.x); lds[g * 4 + 0][n] = h | ((uint)bf16rn(v.x - bf2f(h)) << 16);
        h = bf16rn(v.y); lds[g * 4 + 1][n] = h | ((uint)bf16rn(v.y - bf2f(h)) << 16);
        h = bf16rn(v.z); lds[g * 4 + 2][n] = h | ((uint)bf16rn(v.z - bf2f(h)) << 16);
        h = bf16rn(v.w); lds[g * 4 + 3][n] = h | ((uint)bf16rn(v.w - bf2f(h)) << 16);
    }
    __syncthreads();
    ushort* EH = us + ETH + b * (NC * NN);
    ushort* EL = us + ETL + b * (NC * NN);
    int c = t >> 3, q = t & 7;
#pragma unroll
    for (int i = 0; i < 2; ++i) {
        int cc = c + i * 32;
        uint a0 = lds[cc][q * 8 + 0], a1 = lds[cc][q * 8 + 1], a2 = lds[cc][q * 8 + 2], a3 = lds[cc][q * 8 + 3];
        uint a4 = lds[cc][q * 8 + 4], a5 = lds[cc][q * 8 + 5], a6 = lds[cc][q * 8 + 6], a7 = lds[cc][q * 8 + 7];
        uint4 hv = {(a0 & 0xffffu) | (a1 << 16), (a2 & 0xffffu) | (a3 << 16),
                    (a4 & 0xffffu) | (a5 << 16), (a6 & 0xffffu) | (a7 << 16)};
        uint4 lv = {(a0 >> 16) | (a1 & 0xffff0000u), (a2 >> 16) | (a3 & 0xffff0000u),
                    (a4 >> 16) | (a5 & 0xffff0000u), (a6 >> 16) | (a7 & 0xffff0000u)};
        *(uint4*)(EH + (c0 + cc) * NN + n0 + q * 8) = hv;
        *(uint4*)(EL + (c0 + cc) * NN + n0 + q * 8) = lv;
    }
}

static __device__ const int TI1[10] = {0, 0, 0, 0, 1, 1, 1, 2, 2, 3};
static __device__ const int TI2[10] = {0, 1, 2, 3, 1, 2, 3, 2, 3, 3};

// gram split-K partials over Et, triangular tiles. grid (10, 16, 2)
__global__ __launch_bounds__(256) void k_gram(const ushort* __restrict__ us, float* __restrict__ gp) {
    __shared__ ushort lds[16384];
    ushort* Ah = lds; ushort* Al = lds + 4096; ushort* Bh = lds + 8192; ushort* Bl = lds + 12288;
    int tile = blockIdx.x, kc = blockIdx.y, b = blockIdx.z;
    int c1 = TI1[tile] * 64, c2 = TI2[tile] * 64;
    bool diag = (c1 == c2);
    const ushort* eh = us + ETH + b * (NC * NN);
    const ushort* el = us + ETL + b * (NC * NN);
    int w = threadIdx.x >> 6;
    int wm = (w >> 1) * 32, wn = (w & 1) * 32;
    f32x4 acc[2][2] = {{{0.f, 0.f, 0.f, 0.f}, {0.f, 0.f, 0.f, 0.f}},
                       {{0.f, 0.f, 0.f, 0.f}, {0.f, 0.f, 0.f, 0.f}}};
    for (int kb = 0; kb < 8; ++kb) {
        int n0 = kc * 512 + kb * 64;
        stage64(Ah, eh, c1, n0, NN);
        stage64(Al, el, c1, n0, NN);
        if (!diag) { stage64(Bh, eh, c2, n0, NN); stage64(Bl, el, c2, n0, NN); }
        __syncthreads();
        mfma_tile(Ah, Al, diag ? Ah : Bh, diag ? Al : Bl, wm, wn, acc);
        __syncthreads();
    }
    ep_f32(gp + ((b * 16 + kc) * 10 + tile) * 4096, 64, 0, 0, acc);
}

// reduce 16 gram partials per tri tile, split -> G hi/lo, mirror off-diag. grid (10, 2)
__global__ __launch_bounds__(256) void k_s2(const float* __restrict__ gp, ushort* __restrict__ us) {
    __shared__ float T[64][65];
    int tile = blockIdx.x, b = blockIdx.y;
    int c1 = TI1[tile] * 64, c2 = TI2[tile] * 64;
    int t = threadIdx.x;
    const float* src = gp + (b * 160 + tile) * 4096;
    ushort* GH = us + GHH + b * 65536;
    ushort* GL = us + GHL + b * 65536;
    float4 s[4] = {{0.f, 0.f, 0.f, 0.f}, {0.f, 0.f, 0.f, 0.f}, {0.f, 0.f, 0.f, 0.f}, {0.f, 0.f, 0.f, 0.f}};
    for (int kc = 0; kc < 16; ++kc) {
        const float4* p = (const float4*)(src + kc * 40960);
#pragma unroll
        for (int k2 = 0; k2 < 4; ++k2) {
            float4 v = p[t + k2 * 256];
            s[k2].x += v.x; s[k2].y += v.y; s[k2].z += v.z; s[k2].w += v.w;
        }
    }
#pragma unroll
    for (int k2 = 0; k2 < 4; ++k2) {
        int f = t + k2 * 256;
        int r = f >> 4, c = (f & 15) * 4;
        ushort h0 = bf16rn(s[k2].x), h1 = bf16rn(s[k2].y), h2 = bf16rn(s[k2].z), h3 = bf16rn(s[k2].w);
        ushort e0 = bf16rn(s[k2].x - bf2f(h0)), e1 = bf16rn(s[k2].y - bf2f(h1));
        ushort e2 = bf16rn(s[k2].z - bf2f(h2)), e3 = bf16rn(s[k2].w - bf2f(h3));
        ushort4 hv = {h0, h1, h2, h3}, lv = {e0, e1, e2, e3};
        *(ushort4*)(GH + (c1 + r) * NC + c2 + c) = hv;
        *(ushort4*)(GL + (c1 + r) * NC + c2 + c) = lv;
        T[r][c + 0] = s[k2].x; T[r][c + 1] = s[k2].y; T[r][c + 2] = s[k2].z; T[r][c + 3] = s[k2].w;
    }
    if (c1 != c2) {
        __syncthreads();
#pragma unroll
        for (int k2 = 0; k2 < 4; ++k2) {
            int f = t + k2 * 256;
            int r = f >> 4, c = (f & 15) * 4;
            float a0 = T[c + 0][r], a1 = T[c + 1][r], a2 = T[c + 2][r], a3 = T[c + 3][r];
            ushort h0 = bf16rn(a0), h1 = bf16rn(a1), h2 = bf16rn(a2), h3 = bf16rn(a3);
            ushort e0 = bf16rn(a0 - bf2f(h0)), e1 = bf16rn(a1 - bf2f(h1));
            ushort e2 = bf16rn(a2 - bf2f(h2)), e3 = bf16rn(a3 - bf2f(h3));
            ushort4 hv = {h0, h1, h2, h3}, lv = {e0, e1, e2, e3};
            *(ushort4*)(GH + (c2 + r) * NC + c1 + c) = hv;
            *(ushort4*)(GL + (c2 + r) * NC + c1 + c) = lv;
        }
    }
}

// fused: attn_h = (Wq_h^T G) Wk_h ; instnorm-scale ; softmax ; write SM hi/lo.
// one block per bh, 8 waves, 128 KB LDS. grid (16), block 512.
__global__ __launch_bounds__(512, 2) void k_qksm(ushort* __restrict__ us) {
    __shared__ ushort lds[65536];
    __shared__ float red[17];
    ushort* Ah = lds;            // 256x64 tile (WQT, then T1c)
    ushort* Al = lds + 16384;
    ushort* Bh = lds + 32768;    // 256x64 tile (G uses 64 rows, then WKT)
    ushort* Bl = lds + 49152;
    int bh = blockIdx.x, b = bh >> 3, h = bh & 7;
    int l = threadIdx.x & 63, w = threadIdx.x >> 6;
    const ushort* GH = us + GHH + b * 65536;
    const ushort* GL = us + GHL + b * 65536;
    f32x4 att[2][16];
#pragma unroll
    for (int mt = 0; mt < 2; ++mt)
#pragma unroll
        for (int ct = 0; ct < 16; ++ct) att[mt][ct] = {0.f, 0.f, 0.f, 0.f};

    for (int cc = 0; cc < 4; ++cc) {
        // phase A: T1c[d][ccol] = sum_c' WQT[h*256+d][c'] * G[cc*64+ccol][c']
        f32x4 t1[2][4];
#pragma unroll
        for (int mt = 0; mt < 2; ++mt)
#pragma unroll
            for (int ct = 0; ct < 4; ++ct) t1[mt][ct] = {0.f, 0.f, 0.f, 0.f};
        for (int kk = 0; kk < 4; ++kk) {
            stg<256>(Ah, us + WQTH, h * 256, kk * 64, NC);
            stg<256>(Al, us + WQTL, h * 256, kk * 64, NC);
            stg<64>(Bh, GH, cc * 64, kk * 64, NC);
            stg<64>(Bl, GL, cc * 64, kk * 64, NC);
            __syncthreads();
#pragma unroll
            for (int ks = 0; ks < 2; ++ks) {
                bf16x8 ah0 = frag64(Ah, w * 32, ks), ah1 = frag64(Ah, w * 32 + 16, ks);
                bf16x8 al0 = frag64(Al, w * 32, ks), al1 = frag64(Al, w * 32 + 16, ks);
#pragma unroll
                for (int ct = 0; ct < 4; ++ct) {
                    bf16x8 bhf = frag64(Bh, ct * 16, ks), blf = frag64(Bl, ct * 16, ks);
                    mac3(t1[0][ct], ah0, al0, bhf, blf);
                    mac3(t1[1][ct], ah1, al1, bhf, blf);
                }
            }
            __syncthreads();
        }
        // relayout t1 acc -> T1c operand tile in Ah/Al (rows d, k=ccol; wave-disjoint rows)
#pragma unroll
        for (int mt = 0; mt < 2; ++mt)
#pragma unroll
            for (int ct = 0; ct < 4; ++ct)
#pragma unroll
                for (int r = 0; r < 4; ++r) {
                    float x = t1[mt][ct][r];
                    int R = w * 32 + mt * 16 + (l >> 4) * 4 + r;
                    int kc = ct * 16 + (l & 15);
                    int byte = R * 128 + ((((kc >> 3) ^ (R & 7)) << 4) | ((kc & 7) << 1));
                    ushort hh = bf16rn(x);
                    *(ushort*)((char*)Ah + byte) = hh;
                    *(ushort*)((char*)Al + byte) = bf16rn(x - bf2f(hh));
                }
        stg<256>(Bh, us + WKTH, h * 256, cc * 64, NC);
        stg<256>(Bl, us + WKTL, h * 256, cc * 64, NC);
        __syncthreads();
        // phase B: attn[d][e] += sum_ccol T1c[d][ccol] * WKT[h*256+e][ccol]
#pragma unroll
        for (int ks = 0; ks < 2; ++ks) {
            bf16x8 ah0 = frag64(Ah, w * 32, ks), ah1 = frag64(Ah, w * 32 + 16, ks);
            bf16x8 al0 = frag64(Al, w * 32, ks), al1 = frag64(Al, w * 32 + 16, ks);
#pragma unroll
            for (int ct = 0; ct < 16; ++ct) {
                bf16x8 bhf = frag64(Bh, ct * 16, ks), blf = frag64(Bl, ct * 16, ks);
                mac3(att[0][ct], ah0, al0, bhf, blf);
                mac3(att[1][ct], ah1, al1, bhf, blf);
            }
        }
        __syncthreads();
    }
    // instnorm stats over whole map (block-local)
    float s = 0.f, ss = 0.f;
#pragma unroll
    for (int mt = 0; mt < 2; ++mt)
#pragma unroll
        for (int ct = 0; ct < 16; ++ct)
#pragma unroll
            for (int r = 0; r < 4; ++r) { float x = att[mt][ct][r]; s += x; ss += x * x; }
#pragma unroll
    for (int o = 32; o > 0; o >>= 1) { s += __shfl_xor(s, o); ss += __shfl_xor(ss, o); }
    if (l == 0) { red[w] = s; red[8 + w] = ss; }
    __syncthreads();
    if (threadIdx.x == 0) {
        float S = 0.f, SS = 0.f;
#pragma unroll
        for (int i = 0; i < 8; ++i) { S += red[i]; SS += red[8 + i]; }
        float mu = S * (1.f / 65536.f);
        float var = SS * (1.f / 65536.f) - mu * mu;
        red[16] = rsqrtf(var + EPS);
    }
    __syncthreads();
    float rs = red[16];
    // row softmax (row R spans ct in-register x 16 lanes sharing l>>4)
#pragma unroll
    for (int mt = 0; mt < 2; ++mt)
#pragma unroll
        for (int r = 0; r < 4; ++r) {
            float m = -1e30f;
#pragma unroll
            for (int ct = 0; ct < 16; ++ct) { att[mt][ct][r] *= rs; m = fmaxf(m, att[mt][ct][r]); }
            m = fmaxf(m, __shfl_xor(m, 1)); m = fmaxf(m, __shfl_xor(m, 2));
            m = fmaxf(m, __shfl_xor(m, 4)); m = fmaxf(m, __shfl_xor(m, 8));
            float sum = 0.f;
#pragma unroll
            for (int ct = 0; ct < 16; ++ct) {
                float e = __expf(att[mt][ct][r] - m);
                att[mt][ct][r] = e; sum += e;
            }
            sum += __shfl_xor(sum, 1); sum += __shfl_xor(sum, 2);
            sum += __shfl_xor(sum, 4); sum += __shfl_xor(sum, 8);
            float inv = 1.f / sum;
#pragma unroll
            for (int ct = 0; ct < 16; ++ct) att[mt][ct][r] *= inv;
        }
    // store SM hi/lo
    ushort* dh = us + SMH + bh * 65536;
    ushort* dl = us + SML + bh * 65536;
#pragma unroll
    for (int mt = 0; mt < 2; ++mt)
#pragma unroll
        for (int ct = 0; ct < 16; ++ct)
#pragma unroll
            for (int r = 0; r < 4; ++r) {
                float x = att[mt][ct][r];
                int R = w * 32 + mt * 16 + (l >> 4) * 4 + r;
                int col = ct * 16 + (l & 15);
                ushort hh = bf16rn(x);
                dh[R * 256 + col] = hh;
                dl[R * 256 + col] = bf16rn(x - bf2f(hh));
            }
}

// fused: M = Wv_h SM^T ; Ptp[bh] = Wor_h M^T. one block per bh. grid (16), block 512.
__global__ __launch_bounds__(512, 2) void k_ctx(const ushort* __restrict__ us, float* __restrict__ ptp) {
    __shared__ ushort lds[65536];
    ushort* Ah = lds;            // Wv tile, then Mchunk
    ushort* Al = lds + 16384;
    ushort* Bh = lds + 32768;    // SM tile (64 rows), then WOR
    ushort* Bl = lds + 49152;
    int bh = blockIdx.x, h = bh & 7;
    int l = threadIdx.x & 63, w = threadIdx.x >> 6;
    f32x4 pt[2][16];
#pragma unroll
    for (int mt = 0; mt < 2; ++mt)
#pragma unroll
        for (int ct = 0; ct < 16; ++ct) pt[mt][ct] = {0.f, 0.f, 0.f, 0.f};

    for (int dc = 0; dc < 4; ++dc) {
        // phase A: Mchunk[c][dcol] = sum_e Wv[c][h*256+e] * SM[dc*64+dcol][e]
        f32x4 mc[2][4];
#pragma unroll
        for (int mt = 0; mt < 2; ++mt)
#pragma unroll
            for (int ct = 0; ct < 4; ++ct) mc[mt][ct] = {0.f, 0.f, 0.f, 0.f};
        for (int kk = 0; kk < 4; ++kk) {
            stg<256>(Ah, us + WVH, 0, h * 256 + kk * 64, NCH);
            stg<256>(Al, us + WVL, 0, h * 256 + kk * 64, NCH);
            stg<64>(Bh, us + SMH + bh * 65536, dc * 64, kk * 64, NC);
            stg<64>(Bl, us + SML + bh * 65536, dc * 64, kk * 64, NC);
            __syncthreads();
#pragma unroll
            for (int ks = 0; ks < 2; ++ks) {
                bf16x8 ah0 = frag64(Ah, w * 32, ks), ah1 = frag64(Ah, w * 32 + 16, ks);
                bf16x8 al0 = frag64(Al, w * 32, ks), al1 = frag64(Al, w * 32 + 16, ks);
#pragma unroll
                for (int ct = 0; ct < 4; ++ct) {
                    bf16x8 bhf = frag64(Bh, ct * 16, ks), blf = frag64(Bl, ct * 16, ks);
                    mac3(mc[0][ct], ah0, al0, bhf, blf);
                    mac3(mc[1][ct], ah1, al1, bhf, blf);
                }
            }
            __syncthreads();
        }
        // relayout mc -> Mchunk tile (rows c, k=dcol) in Ah/Al
#pragma unroll
        for (int mt = 0; mt < 2; ++mt)
#pragma unroll
            for (int ct = 0; ct < 4; ++ct)
#pragma unroll
                for (int r = 0; r < 4; ++r) {
                    float x = mc[mt][ct][r];
                    int R = w * 32 + mt * 16 + (l >> 4) * 4 + r;
                    int kc = ct * 16 + (l & 15);
                    int byte = R * 128 + ((((kc >> 3) ^ (R & 7)) << 4) | ((kc & 7) << 1));
                    ushort hh = bf16rn(x);
                    *(ushort*)((char*)Ah + byte) = hh;
                    *(ushort*)((char*)Al + byte) = bf16rn(x - bf2f(hh));
                }
        stg<256>(Bh, us + WORH + h * 65536, 0, dc * 64, NC);
        stg<256>(Bl, us + WORL + h * 65536, 0, dc * 64, NC);
        __syncthreads();
        // phase B: Pt[j][c] += sum_dcol WOR[j][dcol] * Mchunk[c][dcol]
#pragma unroll
        for (int ks = 0; ks < 2; ++ks) {
            bf16x8 ah0 = frag64(Bh, w * 32, ks), ah1 = frag64(Bh, w * 32 + 16, ks);
            bf16x8 al0 = frag64(Bl, w * 32, ks), al1 = frag64(Bl, w * 32 + 16, ks);
#pragma unroll
            for (int ct = 0; ct < 16; ++ct) {
                bf16x8 bhf = frag64(Ah, ct * 16, ks), blf = frag64(Al, ct * 16, ks);
                mac3(pt[0][ct], ah0, al0, bhf, blf);
                mac3(pt[1][ct], ah1, al1, bhf, blf);
            }
        }
        __syncthreads();
    }
    // epilogue: Ptp[bh][j][c]
    float* D = ptp + bh * 65536;
#pragma unroll
    for (int mt = 0; mt < 2; ++mt)
#pragma unroll
        for (int ct = 0; ct < 16; ++ct)
#pragma unroll
            for (int r = 0; r < 4; ++r) {
                int R = w * 32 + mt * 16 + (l >> 4) * 4 + r;
                int col = ct * 16 + (l & 15);
                D[R * 256 + col] = pt[mt][ct][r];
            }
}

// Pt[b] = sum_h Ptp[b*8+h], split -> hi/lo. grid (64, 2)
__global__ __launch_bounds__(256) void k_s4(const float* __restrict__ ptp, ushort* __restrict__ us) {
    int b = blockIdx.y;
    int i = (blockIdx.x * 256 + threadIdx.x) * 4;
    const float* src = ptp + b * 8 * 65536 + i;
    float4 s = {0.f, 0.f, 0.f, 0.f};
#pragma unroll
    for (int h = 0; h < 8; ++h) {
        float4 v = *(const float4*)(src + h * 65536);
        s.x += v.x; s.y += v.y; s.z += v.z; s.w += v.w;
    }
    ushort h0 = bf16rn(s.x), h1 = bf16rn(s.y), h2 = bf16rn(s.z), h3 = bf16rn(s.w);
    ushort e0 = bf16rn(s.x - bf2f(h0)), e1 = bf16rn(s.y - bf2f(h1));
    ushort e2 = bf16rn(s.z - bf2f(h2)), e3 = bf16rn(s.w - bf2f(h3));
    ushort4 hv = {h0, h1, h2, h3}, lv = {e0, e1, e2, e3};
    *(ushort4*)(us + PTH + b * 65536 + i) = hv;
    *(ushort4*)(us + PTL + b * 65536 + i) = lv;
}

// out = emb @ Pt^T. grid (128 nt, 4 jt, 2 b). A split on the fly from fp32.
__global__ __launch_bounds__(256) void k_out(const float* __restrict__ emb, const ushort* __restrict__ us,
                                             float* __restrict__ out) {
    __shared__ ushort lds[16384];
    ushort* Ah = lds; ushort* Al = lds + 4096; ushort* Bh = lds + 8192; ushort* Bl = lds + 12288;
    int nt = blockIdx.x, jt = blockIdx.y, b = blockIdx.z;
    const float* E = emb + b * (NN * NC);
    const ushort* PH = us + PTH + b * 65536;
    const ushort* PL = us + PTL + b * 65536;
    int w = threadIdx.x >> 6;
    int wm = (w >> 1) * 32, wn = (w & 1) * 32;
    f32x4 acc[2][2] = {{{0.f, 0.f, 0.f, 0.f}, {0.f, 0.f, 0.f, 0.f}},
                       {{0.f, 0.f, 0.f, 0.f}, {0.f, 0.f, 0.f, 0.f}}};
    for (int t = 0; t < 4; ++t) {
        stage64_f32(Ah, Al, E, nt * 64, t * 64, NC);
        stage64(Bh, PH, jt * 64, t * 64, NC);
        stage64(Bl, PL, jt * 64, t * 64, NC);
        __syncthreads();
        mfma_tile(Ah, Al, Bh, Bl, wm, wn, acc);
        __syncthreads();
    }
    ep_f32(out + b * (NN * NC), NC, nt * 64, jt * 64, acc);
}

// ---------------------------------------------------------------------------

extern "C" void kernel_launch(void* const* d_in, const int* in_sizes, int n_in,
                              void* d_out, int out_size, void* d_ws, size_t ws_size,
                              hipStream_t stream) {
    const float* emb = (const float*)d_in[0];
    const float* Wq  = (const float*)d_in[1];
    const float* Wk  = (const float*)d_in[2];
    const float* Wv  = (const float*)d_in[3];
    const float* Wo  = (const float*)d_in[4];
    float* out = (float*)d_out;
    float* ws  = (float*)d_ws;

    float* Gp  = ws;                 // [2][16][10][4096]
    float* Ptp = ws + 1310720;       // [16][65536]
    ushort* us = (ushort*)(ws + 2359296);

    k_prep<<<dim3(512, 4),     dim3(256), 0, stream>>>(Wq, Wk, Wv, Wo, us);
    k_s0  <<<dim3(128, 4, NB), dim3(256), 0, stream>>>(emb, us);
    k_gram<<<dim3(10, 16, NB), dim3(256), 0, stream>>>(us, Gp);
    k_s2  <<<dim3(10, NB),     dim3(256), 0, stream>>>(Gp, us);
    k_qksm<<<dim3(16),         dim3(512), 0, stream>>>(us);
    k_ctx <<<dim3(16),         dim3(512), 0, stream>>>(us, Ptp);
    k_s4  <<<dim3(64, NB),     dim3(256), 0, stream>>>(Ptp, us);
    k_out <<<dim3(128, 4, NB), dim3(256), 0, stream>>>(emb, us, out);
}

// Round 6
// 185.045 us; speedup vs baseline: 1.6416x; 1.6416x over previous
//
#include <hip/hip_runtime.h>
#include <hip/hip_bf16.h>

#define NB 2
#define NN 8192
#define NC 256
#define NH 8
#define NCH 2048

static constexpr float EPS = 1e-5f;

// ---------------------------------------------------------------------------
// Factorization (per batch b, head h):
//   G = emb^T emb                       [256x256] (tri tiles, split-K)
//   attn_h = (Wq_h^T G) Wk_h            (k_qk: T1 slice in LDS, grid 256)
//   SM = softmax(attn * rsqrt(var+eps)) (mean shift cancels)
//   M = Wv_h SM^T ; Pt_h = Wor_h M^T    (k_ctx2: M slice in LDS, grid 256)
//   out = emb @ Pt^T,  Pt = sum_h Pt_h
// All GEMM operands bf16 hi/lo pairs: x = hi+lo; acc += hi*hi + hi*lo + lo*hi.
// ---------------------------------------------------------------------------

typedef __attribute__((ext_vector_type(8))) short bf16x8;
typedef __attribute__((ext_vector_type(4))) float f32x4;

#define MFMA16(a, b, c) __builtin_amdgcn_mfma_f32_16x16x32_bf16(a, b, c, 0, 0, 0)

// ---- ws layout -------------------------------------------------------------
// float region:
//   Gp   [2][16][10][4096] @ 0        (1,310,720); attn [16][65536] aliases it
//   Ptp  [16][256][256]    @ 1310720
//   stats[64]              @ 2359296
// ushort region at float offset 2359360:
static constexpr int ETH  = 0;         // Et hi [2][256][8192]
static constexpr int ETL  = 4194304;
static constexpr int WQTH = 8388608;   // Wq^T hi [2048][256]
static constexpr int WQTL = 8912896;
static constexpr int WKTH = 9437184;
static constexpr int WKTL = 9961472;
static constexpr int WVH  = 10485760;  // Wv hi [256][2048]
static constexpr int WVL  = 11010048;
static constexpr int WORH = 11534336;  // Wor hi [8][256][256]: Wor[h][j][d] = Wo[d*8+h][j]
static constexpr int WORL = 12058624;
static constexpr int GHH  = 12582912;  // G hi [2][256][256]
static constexpr int GHL  = 12713984;
static constexpr int SMH  = 12845056;  // softmax hi [16][256][256]
static constexpr int SML  = 13893632;
static constexpr int PTH  = 14942208;  // Pt hi [2][256][256]
static constexpr int PTL  = 15073280;

// ---- helpers ---------------------------------------------------------------

__device__ __forceinline__ ushort bf16rn(float x) {
    uint u = __float_as_uint(x);
    return (ushort)((u + 0x7fffu + ((u >> 16) & 1u)) >> 16);
}
__device__ __forceinline__ float bf2f(ushort h) { return __uint_as_float(((uint)h) << 16); }

// stage 64x64 bf16 tile (k-contiguous source) into XOR-swizzled LDS (256 thr).
__device__ __forceinline__ void stage64(ushort* __restrict__ lds, const ushort* __restrict__ src,
                                        int row0, int k0, int ld) {
    int t = threadIdx.x;
    int g = t & 7, r = t >> 3;
#pragma unroll
    for (int i = 0; i < 2; ++i, r += 32) {
        uint4 v = *(const uint4*)(src + (row0 + r) * ld + k0 + g * 8);
        *(uint4*)((char*)lds + r * 128 + ((g ^ (r & 7)) << 4)) = v;
    }
}

// same, 512 threads, NR rows, 64-wide k (128B rows)
template <int NR>
__device__ __forceinline__ void stg(ushort* __restrict__ lds, const ushort* __restrict__ src,
                                    int row0, int k0, int ld) {
    int t = threadIdx.x;
    int g = t & 7, r = t >> 3;
#pragma unroll
    for (int i = 0; i < NR / 64; ++i) {
        int rr = r + i * 64;
        uint4 v = *(const uint4*)(src + (row0 + rr) * ld + k0 + g * 8);
        *(uint4*)((char*)lds + rr * 128 + ((g ^ (rr & 7)) << 4)) = v;
    }
}

// stage [64 rows][256 k] tile (512B rows), 512 threads
__device__ __forceinline__ void stage_w256(ushort* __restrict__ lds, const ushort* __restrict__ src,
                                           int row0, int k0, int ld) {
    int t = threadIdx.x;
    int g = t & 31, r = t >> 5;
#pragma unroll
    for (int i = 0; i < 4; ++i) {
        int rr = r + i * 16;
        uint4 v = *(const uint4*)(src + (row0 + rr) * ld + k0 + g * 8);
        *(uint4*)((char*)lds + rr * 512 + ((g ^ (rr & 7)) << 4)) = v;
    }
}

// stage 64x64 from fp32 source with on-the-fly hi/lo split (256 thr)
__device__ __forceinline__ void stage64_f32(ushort* __restrict__ ldsh, ushort* __restrict__ ldsl,
                                            const float* __restrict__ src, int row0, int k0, int ld) {
    int t = threadIdx.x;
    int g = t & 15, r = t >> 4;
#pragma unroll
    for (int i = 0; i < 4; ++i, r += 16) {
        float4 v = *(const float4*)(src + (row0 + r) * ld + k0 + g * 4);
        ushort h0 = bf16rn(v.x), h1 = bf16rn(v.y), h2 = bf16rn(v.z), h3 = bf16rn(v.w);
        ushort e0 = bf16rn(v.x - bf2f(h0)), e1 = bf16rn(v.y - bf2f(h1));
        ushort e2 = bf16rn(v.z - bf2f(h2)), e3 = bf16rn(v.w - bf2f(h3));
        int byte = r * 128 + ((((g >> 1) ^ (r & 7)) << 4) | ((g & 1) << 3));
        ushort4 hv = {h0, h1, h2, h3}, lv = {e0, e1, e2, e3};
        *(ushort4*)((char*)ldsh + byte) = hv;
        *(ushort4*)((char*)ldsl + byte) = lv;
    }
}

// fragment from [*][64]-k tile (128B rows)
__device__ __forceinline__ bf16x8 frag64(const ushort* __restrict__ lds, int rbase, int ks) {
    int l = threadIdx.x & 63;
    int r = rbase + (l & 15);
    int slot = (ks * 4 + (l >> 4)) ^ (r & 7);
    return *(const bf16x8*)((const char*)lds + r * 128 + slot * 16);
}

// fragment from [64][256]-k tile (512B rows)
__device__ __forceinline__ bf16x8 frag256(const ushort* __restrict__ lds, int rbase, int ks) {
    int l = threadIdx.x & 63;
    int r = rbase + (l & 15);
    int slot = ((ks << 2) + (l >> 4)) ^ (r & 7);
    return *(const bf16x8*)((const char*)lds + r * 512 + slot * 16);
}

// hi/lo scalar store into [64][256]-k swizzled tile
__device__ __forceinline__ void rl_store(ushort* __restrict__ H, ushort* __restrict__ L,
                                         int R, int col, float x) {
    int byte = R * 512 + ((((col >> 3) ^ (R & 7)) << 4) | ((col & 7) << 1));
    ushort hh = bf16rn(x);
    *(ushort*)((char*)H + byte) = hh;
    *(ushort*)((char*)L + byte) = bf16rn(x - bf2f(hh));
}

__device__ __forceinline__ void mac3(f32x4& acc, bf16x8 ah, bf16x8 al, bf16x8 bh, bf16x8 bl) {
    acc = MFMA16(ah, bh, acc);
    acc = MFMA16(ah, bl, acc);
    acc = MFMA16(al, bh, acc);
}

// 4-wave 64x64 mfma over one staged k-tile (256-thr kernels)
__device__ __forceinline__ void mfma_tile(const ushort* Ah, const ushort* Al,
                                          const ushort* Bh, const ushort* Bl,
                                          int wm, int wn, f32x4 acc[2][2]) {
#pragma unroll
    for (int ks = 0; ks < 2; ++ks) {
        bf16x8 ah[2], al[2], bh[2], bl[2];
        ah[0] = frag64(Ah, wm, ks);      ah[1] = frag64(Ah, wm + 16, ks);
        al[0] = frag64(Al, wm, ks);      al[1] = frag64(Al, wm + 16, ks);
        bh[0] = frag64(Bh, wn, ks);      bh[1] = frag64(Bh, wn + 16, ks);
        bl[0] = frag64(Bl, wn, ks);      bl[1] = frag64(Bl, wn + 16, ks);
#pragma unroll
        for (int mi = 0; mi < 2; ++mi)
#pragma unroll
            for (int ni = 0; ni < 2; ++ni)
                mac3(acc[mi][ni], ah[mi], al[mi], bh[ni], bl[ni]);
    }
}

__device__ __forceinline__ void ep_f32(float* D, int ld, int row0, int col0, f32x4 acc[2][2]) {
    int l = threadIdx.x & 63, w = threadIdx.x >> 6;
    int wm = (w >> 1) * 32, wn = (w & 1) * 32;
#pragma unroll
    for (int mi = 0; mi < 2; ++mi)
#pragma unroll
        for (int ni = 0; ni < 2; ++ni)
#pragma unroll
            for (int r = 0; r < 4; ++r)
                D[(row0 + wm + mi * 16 + (l >> 4) * 4 + r) * ld + col0 + wn + ni * 16 + (l & 15)] = acc[mi][ni][r];
}

// transpose+split a 64x64 fp32 tile: src[m*srcStride + j] -> dst[j*NC + m] (hi/lo)
__device__ __forceinline__ void tsplit(uint (*lds)[65], const float* __restrict__ src, int srcStride,
                                       ushort* __restrict__ DH, ushort* __restrict__ DL) {
    int t = threadIdx.x;
    int r = t >> 4, g = t & 15;
#pragma unroll
    for (int i = 0; i < 4; ++i) {
        int m = r + i * 16;
        float4 v = *(const float4*)(src + m * srcStride + g * 4);
        ushort h;
        h = bf16rn(v.x); lds[g * 4 + 0][m] = h | ((uint)bf16rn(v.x - bf2f(h)) << 16);
        h = bf16rn(v.y); lds[g * 4 + 1][m] = h | ((uint)bf16rn(v.y - bf2f(h)) << 16);
        h = bf16rn(v.z); lds[g * 4 + 2][m] = h | ((uint)bf16rn(v.z - bf2f(h)) << 16);
        h = bf16rn(v.w); lds[g * 4 + 3][m] = h | ((uint)bf16rn(v.w - bf2f(h)) << 16);
    }
    __syncthreads();
    int j = t >> 3, q = t & 7;
#pragma unroll
    for (int i = 0; i < 2; ++i) {
        int jj = j + i * 32;
        uint a0 = lds[jj][q * 8 + 0], a1 = lds[jj][q * 8 + 1], a2 = lds[jj][q * 8 + 2], a3 = lds[jj][q * 8 + 3];
        uint a4 = lds[jj][q * 8 + 4], a5 = lds[jj][q * 8 + 5], a6 = lds[jj][q * 8 + 6], a7 = lds[jj][q * 8 + 7];
        uint4 hv = {(a0 & 0xffffu) | (a1 << 16), (a2 & 0xffffu) | (a3 << 16),
                    (a4 & 0xffffu) | (a5 << 16), (a6 & 0xffffu) | (a7 << 16)};
        uint4 lv = {(a0 >> 16) | (a1 & 0xffff0000u), (a2 >> 16) | (a3 & 0xffff0000u),
                    (a4 >> 16) | (a5 & 0xffff0000u), (a6 >> 16) | (a7 & 0xffff0000u)};
        *(uint4*)(DH + jj * NC + q * 8) = hv;
        *(uint4*)(DL + jj * NC + q * 8) = lv;
    }
}

// ---- kernels ---------------------------------------------------------------

// weight prep: z=0 Wq^T, z=1 Wk^T, z=2 Wo rearrange, z=3 Wv split + zero stats
__global__ __launch_bounds__(256) void k_prep(const float* __restrict__ wq, const float* __restrict__ wk,
                                              const float* __restrict__ wv, const float* __restrict__ wo,
                                              ushort* __restrict__ us, float* __restrict__ stats) {
    __shared__ uint lds[64][65];
    int x = blockIdx.x, z = blockIdx.y;
    int t = threadIdx.x;
    if (z == 3) {
        if (x == 0 && t < 64) stats[t] = 0.f;
        int i = (x * 256 + t) * 4;
        float4 v = *(const float4*)(wv + i);
        ushort h0 = bf16rn(v.x), h1 = bf16rn(v.y), h2 = bf16rn(v.z), h3 = bf16rn(v.w);
        ushort e0 = bf16rn(v.x - bf2f(h0)), e1 = bf16rn(v.y - bf2f(h1));
        ushort e2 = bf16rn(v.z - bf2f(h2)), e3 = bf16rn(v.w - bf2f(h3));
        ushort4 hv = {h0, h1, h2, h3}, lv = {e0, e1, e2, e3};
        *(ushort4*)(us + WVH + i) = hv;
        *(ushort4*)(us + WVL + i) = lv;
        return;
    }
    if (x >= 128) return;
    if (z == 2) {
        int h = x >> 4, dt = (x >> 2) & 3, jt = x & 3;
        tsplit(lds, wo + (dt * 64 * 8 + h) * NC + jt * 64, 8 * NC,
               us + WORH + h * 65536 + (jt * 64) * NC + dt * 64,
               us + WORL + h * 65536 + (jt * 64) * NC + dt * 64);
        return;
    }
    int jt = x >> 2, ct = x & 3;
    const float* W = z ? wk : wq;
    int dh = (z ? WKTH : WQTH) + (jt * 64) * NC + ct * 64;
    int dl = (z ? WKTL : WQTL) + (jt * 64) * NC + ct * 64;
    tsplit(lds, W + (ct * 64) * NCH + jt * 64, NCH, us + dh, us + dl);
}

// emb -> Et hi/lo [b][c][n] (transpose + split). grid (128 nt, 4 ct, 2 b)
__global__ __launch_bounds__(256) void k_s0(const float* __restrict__ emb, ushort* __restrict__ us) {
    __shared__ uint lds[64][65];
    int nt = blockIdx.x, ct = blockIdx.y, b = blockIdx.z;
    int t = threadIdx.x;
    const float* E = emb + b * (NN * NC);
    int n0 = nt * 64, c0 = ct * 64;
    int r = t >> 4, g = t & 15;
#pragma unroll
    for (int i = 0; i < 4; ++i) {
        int n = r + i * 16;
        float4 v = *(const float4*)(E + (n0 + n) * NC + c0 + g * 4);
        ushort h;
        h = bf16rn(v.x); lds[g * 4 + 0][n] = h | ((uint)bf16rn(v.x - bf2f(h)) << 16);
        h = bf16rn(v.y); lds[g * 4 + 1][n] = h | ((uint)bf16rn(v.y - bf2f(h)) << 16);
        h = bf16rn(v.z); lds[g * 4 + 2][n] = h | ((uint)bf16rn(v.z - bf2f(h)) << 16);
        h = bf16rn(v.w); lds[g * 4 + 3][n] = h | ((uint)bf16rn(v.w - bf2f(h)) << 16);
    }
    __syncthreads();
    ushort* EH = us + ETH + b * (NC * NN);
    ushort* EL = us + ETL + b * (NC * NN);
    int c = t >> 3, q = t & 7;
#pragma unroll
    for (int i = 0; i < 2; ++i) {
        int cc = c + i * 32;
        uint a0 = lds[cc][q * 8 + 0], a1 = lds[cc][q * 8 + 1], a2 = lds[cc][q * 8 + 2], a3 = lds[cc][q * 8 + 3];
        uint a4 = lds[cc][q * 8 + 4], a5 = lds[cc][q * 8 + 5], a6 = lds[cc][q * 8 + 6], a7 = lds[cc][q * 8 + 7];
        uint4 hv = {(a0 & 0xffffu) | (a1 << 16), (a2 & 0xffffu) | (a3 << 16),
                    (a4 & 0xffffu) | (a5 << 16), (a6 & 0xffffu) | (a7 << 16)};
        uint4 lv = {(a0 >> 16) | (a1 & 0xffff0000u), (a2 >> 16) | (a3 & 0xffff0000u),
                    (a4 >> 16) | (a5 & 0xffff0000u), (a6 >> 16) | (a7 & 0xffff0000u)};
        *(uint4*)(EH + (c0 + cc) * NN + n0 + q * 8) = hv;
        *(uint4*)(EL + (c0 + cc) * NN + n0 + q * 8) = lv;
    }
}

static __device__ const int TI1[10] = {0, 0, 0, 0, 1, 1, 1, 2, 2, 3};
static __device__ const int TI2[10] = {0, 1, 2, 3, 1, 2, 3, 2, 3, 3};

// gram split-K partials over Et, triangular tiles. grid (10, 16, 2)
__global__ __launch_bounds__(256) void k_gram(const ushort* __restrict__ us, float* __restrict__ gp) {
    __shared__ ushort lds[16384];
    ushort* Ah = lds; ushort* Al = lds + 4096; ushort* Bh = lds + 8192; ushort* Bl = lds + 12288;
    int tile = blockIdx.x, kc = blockIdx.y, b = blockIdx.z;
    int c1 = TI1[tile] * 64, c2 = TI2[tile] * 64;
    bool diag = (c1 == c2);
    const ushort* eh = us + ETH + b * (NC * NN);
    const ushort* el = us + ETL + b * (NC * NN);
    int w = threadIdx.x >> 6;
    int wm = (w >> 1) * 32, wn = (w & 1) * 32;
    f32x4 acc[2][2] = {{{0.f, 0.f, 0.f, 0.f}, {0.f, 0.f, 0.f, 0.f}},
                       {{0.f, 0.f, 0.f, 0.f}, {0.f, 0.f, 0.f, 0.f}}};
    for (int kb = 0; kb < 8; ++kb) {
        int n0 = kc * 512 + kb * 64;
        stage64(Ah, eh, c1, n0, NN);
        stage64(Al, el, c1, n0, NN);
        if (!diag) { stage64(Bh, eh, c2, n0, NN); stage64(Bl, el, c2, n0, NN); }
        __syncthreads();
        mfma_tile(Ah, Al, diag ? Ah : Bh, diag ? Al : Bl, wm, wn, acc);
        __syncthreads();
    }
    ep_f32(gp + ((b * 16 + kc) * 10 + tile) * 4096, 64, 0, 0, acc);
}

// reduce 16 gram partials per tri tile, split -> G hi/lo, mirror off-diag. grid (10, 2)
__global__ __launch_bounds__(256) void k_s2(const float* __restrict__ gp, ushort* __restrict__ us) {
    __shared__ float T[64][65];
    int tile = blockIdx.x, b = blockIdx.y;
    int c1 = TI1[tile] * 64, c2 = TI2[tile] * 64;
    int t = threadIdx.x;
    const float* src = gp + (b * 160 + tile) * 4096;
    ushort* GH = us + GHH + b * 65536;
    ushort* GL = us + GHL + b * 65536;
    float4 s[4] = {{0.f, 0.f, 0.f, 0.f}, {0.f, 0.f, 0.f, 0.f}, {0.f, 0.f, 0.f, 0.f}, {0.f, 0.f, 0.f, 0.f}};
    for (int kc = 0; kc < 16; ++kc) {
        const float4* p = (const float4*)(src + kc * 40960);
#pragma unroll
        for (int k2 = 0; k2 < 4; ++k2) {
            float4 v = p[t + k2 * 256];
            s[k2].x += v.x; s[k2].y += v.y; s[k2].z += v.z; s[k2].w += v.w;
        }
    }
#pragma unroll
    for (int k2 = 0; k2 < 4; ++k2) {
        int f = t + k2 * 256;
        int r = f >> 4, c = (f & 15) * 4;
        ushort h0 = bf16rn(s[k2].x), h1 = bf16rn(s[k2].y), h2 = bf16rn(s[k2].z), h3 = bf16rn(s[k2].w);
        ushort e0 = bf16rn(s[k2].x - bf2f(h0)), e1 = bf16rn(s[k2].y - bf2f(h1));
        ushort e2 = bf16rn(s[k2].z - bf2f(h2)), e3 = bf16rn(s[k2].w - bf2f(h3));
        ushort4 hv = {h0, h1, h2, h3}, lv = {e0, e1, e2, e3};
        *(ushort4*)(GH + (c1 + r) * NC + c2 + c) = hv;
        *(ushort4*)(GL + (c1 + r) * NC + c2 + c) = lv;
        T[r][c + 0] = s[k2].x; T[r][c + 1] = s[k2].y; T[r][c + 2] = s[k2].z; T[r][c + 3] = s[k2].w;
    }
    if (c1 != c2) {
        __syncthreads();
#pragma unroll
        for (int k2 = 0; k2 < 4; ++k2) {
            int f = t + k2 * 256;
            int r = f >> 4, c = (f & 15) * 4;
            float a0 = T[c + 0][r], a1 = T[c + 1][r], a2 = T[c + 2][r], a3 = T[c + 3][r];
            ushort h0 = bf16rn(a0), h1 = bf16rn(a1), h2 = bf16rn(a2), h3 = bf16rn(a3);
            ushort e0 = bf16rn(a0 - bf2f(h0)), e1 = bf16rn(a1 - bf2f(h1));
            ushort e2 = bf16rn(a2 - bf2f(h2)), e3 = bf16rn(a3 - bf2f(h3));
            ushort4 hv = {h0, h1, h2, h3}, lv = {e0, e1, e2, e3};
            *(uint4*)(GH + (c2 + r) * NC + c1 + c) = *(uint4*)&hv;
            *(uint4*)(GL + (c2 + r) * NC + c1 + c) = *(uint4*)&lv;
        }
    }
}

// fused T1+attn: per block one 64x64 attn tile; T1 slice (64x256) lives in LDS.
// grid (16 tiles, 16 bh), 512 threads, 128 KB LDS.
__global__ __launch_bounds__(512, 2) void k_qk(const ushort* __restrict__ us, float* __restrict__ attn,
                                               float* __restrict__ stats) {
    __shared__ ushort lds[65536];
    int tile = blockIdx.x, bh = blockIdx.y;
    int dt = tile >> 2, et = tile & 3;
    int b = bh >> 3, h = bh & 7;
    int l = threadIdx.x & 63, w = threadIdx.x >> 6;
    ushort* GAh = lds;            // phase A: G [256 c][64 c']; phase B: T1s [64 d][256 c]
    ushort* GAl = lds + 16384;
    ushort* QAh = lds + 32768;    // phase A: WQT [64 d][64 c']
    ushort* QAl = lds + 36864;
    ushort* WKh = lds + 32768;    // phase B: WKT [64 e][256 c]
    ushort* WKl = lds + 49152;
    const ushort* GH = us + GHH + b * 65536;
    const ushort* GL = us + GHL + b * 65536;

    // phase A: T1[d][c] = sum_c' WQT[hd][c'] G[c][c']   (G symmetric)
    f32x4 t1[4][2];
#pragma unroll
    for (int mi = 0; mi < 4; ++mi)
#pragma unroll
        for (int ni = 0; ni < 2; ++ni) t1[mi][ni] = {0.f, 0.f, 0.f, 0.f};
    for (int kt = 0; kt < 4; ++kt) {
        stg<256>(GAh, GH, 0, kt * 64, NC);
        stg<256>(GAl, GL, 0, kt * 64, NC);
        stg<64>(QAh, us + WQTH, h * 256 + dt * 64, kt * 64, NC);
        stg<64>(QAl, us + WQTL, h * 256 + dt * 64, kt * 64, NC);
        __syncthreads();
#pragma unroll
        for (int ks = 0; ks < 2; ++ks) {
            bf16x8 bhf[2], blf[2];
            bhf[0] = frag64(GAh, w * 32, ks);      bhf[1] = frag64(GAh, w * 32 + 16, ks);
            blf[0] = frag64(GAl, w * 32, ks);      blf[1] = frag64(GAl, w * 32 + 16, ks);
#pragma unroll
            for (int mi = 0; mi < 4; ++mi) {
                bf16x8 ahf = frag64(QAh, mi * 16, ks);
                bf16x8 alf = frag64(QAl, mi * 16, ks);
#pragma unroll
                for (int ni = 0; ni < 2; ++ni)
                    mac3(t1[mi][ni], ahf, alf, bhf[ni], blf[ni]);
            }
        }
        __syncthreads();
    }
    // relayout t1 -> T1s [64 d][256 c] (overwrites G region) + stage WKT
#pragma unroll
    for (int mi = 0; mi < 4; ++mi)
#pragma unroll
        for (int ni = 0; ni < 2; ++ni)
#pragma unroll
            for (int r = 0; r < 4; ++r) {
                int R = mi * 16 + (l >> 4) * 4 + r;
                int col = w * 32 + ni * 16 + (l & 15);
                rl_store(GAh, GAl, R, col, t1[mi][ni][r]);
            }
    stage_w256(WKh, us + WKTH, h * 256 + et * 64, 0, NC);
    stage_w256(WKl, us + WKTL, h * 256 + et * 64, 0, NC);
    __syncthreads();
    // phase B: attn[d][e] = sum_c T1s[d][c] WKT[e][c]
    int wm = (w >> 2) * 32, wn = (w & 3) * 16;
    f32x4 av[2] = {{0.f, 0.f, 0.f, 0.f}, {0.f, 0.f, 0.f, 0.f}};
#pragma unroll
    for (int ks = 0; ks < 8; ++ks) {
        bf16x8 bhf = frag256(WKh, wn, ks);
        bf16x8 blf = frag256(WKl, wn, ks);
#pragma unroll
        for (int mi = 0; mi < 2; ++mi) {
            bf16x8 ahf = frag256(GAh, wm + mi * 16, ks);
            bf16x8 alf = frag256(GAl, wm + mi * 16, ks);
            mac3(av[mi], ahf, alf, bhf, blf);
        }
    }
    // epilogue: write attn fp32 + variance stats
    float* D = attn + bh * 65536;
    float lsum = 0.f, lss = 0.f;
#pragma unroll
    for (int mi = 0; mi < 2; ++mi)
#pragma unroll
        for (int r = 0; r < 4; ++r) {
            float x = av[mi][r];
            int row = dt * 64 + wm + mi * 16 + (l >> 4) * 4 + r;
            int col = et * 64 + wn + (l & 15);
            D[row * 256 + col] = x;
            lsum += x; lss += x * x;
        }
#pragma unroll
    for (int o = 32; o > 0; o >>= 1) { lsum += __shfl_xor(lsum, o); lss += __shfl_xor(lss, o); }
    if (l == 0) { atomicAdd(&stats[bh * 2], lsum); atomicAdd(&stats[bh * 2 + 1], lss); }
}

// fused instnorm-scale + softmax, write hi/lo. grid (16 bh, 4 rb)
__global__ __launch_bounds__(256) void k_sm(const float* __restrict__ attn, const float* __restrict__ stats,
                                            ushort* __restrict__ us) {
    int bh = blockIdx.x, rb = blockIdx.y;
    float mean = stats[bh * 2] * (1.f / 65536.f);
    float var = stats[bh * 2 + 1] * (1.f / 65536.f) - mean * mean;
    float rs = rsqrtf(var + EPS);
    int w = threadIdx.x >> 6, l = threadIdx.x & 63;
    const float* src = attn + bh * 65536;
    ushort* dh = us + SMH + bh * 65536;
    ushort* dl = us + SML + bh * 65536;
    for (int rr = 0; rr < 16; ++rr) {
        int row = rb * 64 + w * 16 + rr;
        float4 v = *(const float4*)(src + row * 256 + l * 4);
        v.x *= rs; v.y *= rs; v.z *= rs; v.w *= rs;
        float mx = fmaxf(fmaxf(v.x, v.y), fmaxf(v.z, v.w));
#pragma unroll
        for (int o = 32; o > 0; o >>= 1) mx = fmaxf(mx, __shfl_xor(mx, o));
        float e0 = __expf(v.x - mx), e1 = __expf(v.y - mx), e2 = __expf(v.z - mx), e3 = __expf(v.w - mx);
        float se = e0 + e1 + e2 + e3;
#pragma unroll
        for (int o = 32; o > 0; o >>= 1) se += __shfl_xor(se, o);
        float inv = 1.f / se;
        e0 *= inv; e1 *= inv; e2 *= inv; e3 *= inv;
        ushort h0 = bf16rn(e0), h1 = bf16rn(e1), h2 = bf16rn(e2), h3 = bf16rn(e3);
        ushort f0 = bf16rn(e0 - bf2f(h0)), f1 = bf16rn(e1 - bf2f(h1));
        ushort f2 = bf16rn(e2 - bf2f(h2)), f3 = bf16rn(e3 - bf2f(h3));
        ushort4 hv = {h0, h1, h2, h3}, lv = {f0, f1, f2, f3};
        *(ushort4*)(dh + row * 256 + l * 4) = hv;
        *(ushort4*)(dl + row * 256 + l * 4) = lv;
    }
}

// fused M+Pt: per block one 64x64 Pt tile; M slice (64x256) lives in LDS.
// grid (16 tiles, 16 bh), 512 threads, 128 KB LDS.
__global__ __launch_bounds__(512, 2) void k_ctx2(const ushort* __restrict__ us, float* __restrict__ ptp) {
    __shared__ ushort lds[65536];
    int tile = blockIdx.x, bh = blockIdx.y;
    int jt = tile >> 2, ct = tile & 3;
    int h = bh & 7;
    int l = threadIdx.x & 63, w = threadIdx.x >> 6;
    ushort* SAh = lds;            // phase A: SM [256 d][64 e]; phase B: Ms [64 c][256 d]
    ushort* SAl = lds + 16384;
    ushort* VAh = lds + 32768;    // phase A: Wv [64 c][64 e]
    ushort* VAl = lds + 36864;
    ushort* WOh = lds + 32768;    // phase B: WOR [64 j][256 d]
    ushort* WOl = lds + 49152;
    const ushort* SH = us + SMH + bh * 65536;
    const ushort* SL = us + SML + bh * 65536;

    // phase A: M[c][d] = sum_e Wv[c][he] SM[d][e]
    f32x4 mc[4][2];
#pragma unroll
    for (int mi = 0; mi < 4; ++mi)
#pragma unroll
        for (int ni = 0; ni < 2; ++ni) mc[mi][ni] = {0.f, 0.f, 0.f, 0.f};
    for (int kt = 0; kt < 4; ++kt) {
        stg<256>(SAh, SH, 0, kt * 64, NC);
        stg<256>(SAl, SL, 0, kt * 64, NC);
        stg<64>(VAh, us + WVH, ct * 64, h * 256 + kt * 64, NCH);
        stg<64>(VAl, us + WVL, ct * 64, h * 256 + kt * 64, NCH);
        __syncthreads();
#pragma unroll
        for (int ks = 0; ks < 2; ++ks) {
            bf16x8 bhf[2], blf[2];
            bhf[0] = frag64(SAh, w * 32, ks);      bhf[1] = frag64(SAh, w * 32 + 16, ks);
            blf[0] = frag64(SAl, w * 32, ks);      blf[1] = frag64(SAl, w * 32 + 16, ks);
#pragma unroll
            for (int mi = 0; mi < 4; ++mi) {
                bf16x8 ahf = frag64(VAh, mi * 16, ks);
                bf16x8 alf = frag64(VAl, mi * 16, ks);
#pragma unroll
                for (int ni = 0; ni < 2; ++ni)
                    mac3(mc[mi][ni], ahf, alf, bhf[ni], blf[ni]);
            }
        }
        __syncthreads();
    }
    // relayout mc -> Ms [64 c][256 d] + stage WOR
#pragma unroll
    for (int mi = 0; mi < 4; ++mi)
#pragma unroll
        for (int ni = 0; ni < 2; ++ni)
#pragma unroll
            for (int r = 0; r < 4; ++r) {
                int R = mi * 16 + (l >> 4) * 4 + r;
                int col = w * 32 + ni * 16 + (l & 15);
                rl_store(SAh, SAl, R, col, mc[mi][ni][r]);
            }
    stage_w256(WOh, us + WORH + h * 65536, jt * 64, 0, NC);
    stage_w256(WOl, us + WORL + h * 65536, jt * 64, 0, NC);
    __syncthreads();
    // phase B: Pt[j][c] = sum_d WOR[j][d] Ms[c][d]
    int wm = (w >> 2) * 32, wn = (w & 3) * 16;
    f32x4 av[2] = {{0.f, 0.f, 0.f, 0.f}, {0.f, 0.f, 0.f, 0.f}};
#pragma unroll
    for (int ks = 0; ks < 8; ++ks) {
        bf16x8 bhf = frag256(SAh, wn, ks);
        bf16x8 blf = frag256(SAl, wn, ks);
#pragma unroll
        for (int mi = 0; mi < 2; ++mi) {
            bf16x8 ahf = frag256(WOh, wm + mi * 16, ks);
            bf16x8 alf = frag256(WOl, wm + mi * 16, ks);
            mac3(av[mi], ahf, alf, bhf, blf);
        }
    }
    // epilogue: Ptp[bh][j][c]
    float* D = ptp + bh * 65536;
#pragma unroll
    for (int mi = 0; mi < 2; ++mi)
#pragma unroll
        for (int r = 0; r < 4; ++r) {
            int row = jt * 64 + wm + mi * 16 + (l >> 4) * 4 + r;
            int col = ct * 64 + wn + (l & 15);
            D[row * 256 + col] = av[mi][r];
        }
}

// Pt[b] = sum_h Ptp[b*8+h], split -> hi/lo. grid (64, 2)
__global__ __launch_bounds__(256) void k_s4(const float* __restrict__ ptp, ushort* __restrict__ us) {
    int b = blockIdx.y;
    int i = (blockIdx.x * 256 + threadIdx.x) * 4;
    const float* src = ptp + b * 8 * 65536 + i;
    float4 s = {0.f, 0.f, 0.f, 0.f};
#pragma unroll
    for (int h = 0; h < 8; ++h) {
        float4 v = *(const float4*)(src + h * 65536);
        s.x += v.x; s.y += v.y; s.z += v.z; s.w += v.w;
    }
    ushort h0 = bf16rn(s.x), h1 = bf16rn(s.y), h2 = bf16rn(s.z), h3 = bf16rn(s.w);
    ushort e0 = bf16rn(s.x - bf2f(h0)), e1 = bf16rn(s.y - bf2f(h1));
    ushort e2 = bf16rn(s.z - bf2f(h2)), e3 = bf16rn(s.w - bf2f(h3));
    ushort4 hv = {h0, h1, h2, h3}, lv = {e0, e1, e2, e3};
    *(ushort4*)(us + PTH + b * 65536 + i) = hv;
    *(ushort4*)(us + PTL + b * 65536 + i) = lv;
}

// out = emb @ Pt^T. grid (128 nt, 4 jt, 2 b). A split on the fly from fp32.
__global__ __launch_bounds__(256) void k_out(const float* __restrict__ emb, const ushort* __restrict__ us,
                                             float* __restrict__ out) {
    __shared__ ushort lds[16384];
    ushort* Ah = lds; ushort* Al = lds + 4096; ushort* Bh = lds + 8192; ushort* Bl = lds + 12288;
    int nt = blockIdx.x, jt = blockIdx.y, b = blockIdx.z;
    const float* E = emb + b * (NN * NC);
    const ushort* PH = us + PTH + b * 65536;
    const ushort* PL = us + PTL + b * 65536;
    int w = threadIdx.x >> 6;
    int wm = (w >> 1) * 32, wn = (w & 1) * 32;
    f32x4 acc[2][2] = {{{0.f, 0.f, 0.f, 0.f}, {0.f, 0.f, 0.f, 0.f}},
                       {{0.f, 0.f, 0.f, 0.f}, {0.f, 0.f, 0.f, 0.f}}};
    for (int t = 0; t < 4; ++t) {
        stage64_f32(Ah, Al, E, nt * 64, t * 64, NC);
        stage64(Bh, PH, jt * 64, t * 64, NC);
        stage64(Bl, PL, jt * 64, t * 64, NC);
        __syncthreads();
        mfma_tile(Ah, Al, Bh, Bl, wm, wn, acc);
        __syncthreads();
    }
    ep_f32(out + b * (NN * NC), NC, nt * 64, jt * 64, acc);
}

// ---------------------------------------------------------------------------

extern "C" void kernel_launch(void* const* d_in, const int* in_sizes, int n_in,
                              void* d_out, int out_size, void* d_ws, size_t ws_size,
                              hipStream_t stream) {
    const float* emb = (const float*)d_in[0];
    const float* Wq  = (const float*)d_in[1];
    const float* Wk  = (const float*)d_in[2];
    const float* Wv  = (const float*)d_in[3];
    const float* Wo  = (const float*)d_in[4];
    float* out = (float*)d_out;
    float* ws  = (float*)d_ws;

    float* Gp    = ws;                 // [2][16][10][4096]
    float* attn  = ws;                 // alias (Gp dead after k_s2)
    float* Ptp   = ws + 1310720;       // [16][65536]
    float* stats = ws + 2359296;       // 64 floats
    ushort* us   = (ushort*)(ws + 2359360);

    k_prep<<<dim3(512, 4),     dim3(256), 0, stream>>>(Wq, Wk, Wv, Wo, us, stats);
    k_s0  <<<dim3(128, 4, NB), dim3(256), 0, stream>>>(emb, us);
    k_gram<<<dim3(10, 16, NB), dim3(256), 0, stream>>>(us, Gp);
    k_s2  <<<dim3(10, NB),     dim3(256), 0, stream>>>(Gp, us);
    k_qk  <<<dim3(16, 16),     dim3(512), 0, stream>>>(us, attn, stats);
    k_sm  <<<dim3(16, 4),      dim3(256), 0, stream>>>(attn, stats, us);
    k_ctx2<<<dim3(16, 16),     dim3(512), 0, stream>>>(us, Ptp);
    k_s4  <<<dim3(64, NB),     dim3(256), 0, stream>>>(Ptp, us);
    k_out <<<dim3(128, 4, NB), dim3(256), 0, stream>>>(emb, us, out);
}

// Round 7
// 172.642 us; speedup vs baseline: 1.7595x; 1.0718x over previous
//
#include <hip/hip_runtime.h>
#include <hip/hip_bf16.h>

#define NB 2
#define NN 8192
#define NC 256
#define NH 8
#define NCH 2048

static constexpr float EPS = 1e-5f;

// ---------------------------------------------------------------------------
// Factorization (per batch b, head h):
//   G = emb^T emb                        [256x256]  (Et staging, tri tiles, split-K)
//   T1[hd][c] = sum_c' Wq[c'][hd] G[c'][c]
//   attn[d][e] = sum_c T1[hd][c] Wk[c][he]          (+ variance stats)
//   SM = softmax(attn * rsqrt(var+eps))             (mean shift cancels)
//   M[c][d] = sum_e Wv[c][he] SM[d][e]
//   Pt[j][c] += sum_d Wor[h][j][d] M[c][d]          (per-h partials)
//   out[n][j] = sum_c emb[n][c] Pt[j][c]            (fp32-split A on the fly)
// All GEMM operands bf16 hi/lo pairs: x = hi + lo; acc += hi*hi + hi*lo + lo*hi.
// Rule learned (r4, r6): every kernel keeps >=256 blocks and <=32 KB LDS so
// 4-5 blocks/CU overlap latency. No mega-fusion.
// ---------------------------------------------------------------------------

typedef __attribute__((ext_vector_type(8))) short bf16x8;
typedef __attribute__((ext_vector_type(4))) float f32x4;

#define MFMA16(a, b, c) __builtin_amdgcn_mfma_f32_16x16x32_bf16(a, b, c, 0, 0, 0)

// ---- ws layout -------------------------------------------------------------
// float region:
//   Gp   [2][16][10][4096] @ 0        (1,310,720) gram split-K tri partials
//   attn [16][256][256]    @ 0        (alias; Gp dead after k_s2)
//   Ptp  [16][256][256]    @ 1310720
//   stats[64]              @ 2359296
// ushort region at float offset 2359360:
static constexpr int ETH  = 0;         // Et hi [2][256][8192]
static constexpr int ETL  = 4194304;
static constexpr int WQTH = 8388608;   // Wq^T hi [2048][256]
static constexpr int WQTL = 8912896;
static constexpr int WKTH = 9437184;
static constexpr int WKTL = 9961472;
static constexpr int WVH  = 10485760;  // Wv hi [256][2048]
static constexpr int WVL  = 11010048;
static constexpr int WORH = 11534336;  // Wor hi [8][256][256]: Wor[h][j][d] = Wo[d*8+h][j]
static constexpr int WORL = 12058624;
static constexpr int GHH  = 12582912;  // G hi [2][256][256]
static constexpr int GHL  = 12713984;
static constexpr int T1H  = 12845056;  // T1 hi [2][2048][256]; reused as M [16][256][256]
static constexpr int T1L  = 13893632;
static constexpr int SMH  = 14942208;  // softmax hi [16][256][256]
static constexpr int SML  = 15990784;
static constexpr int PTH  = 17039360;  // Pt hi [2][256][256]
static constexpr int PTL  = 17170432;

// ---- helpers ---------------------------------------------------------------

__device__ __forceinline__ ushort bf16rn(float x) {
    uint u = __float_as_uint(x);
    return (ushort)((u + 0x7fffu + ((u >> 16) & 1u)) >> 16);
}
__device__ __forceinline__ float bf2f(ushort h) { return __uint_as_float(((uint)h) << 16); }

// stage a 64x64 bf16 tile (k-contiguous source) into XOR-swizzled LDS (256 thr).
// LDS row = m (128 B); 16B slot s within row holds k-group (s ^ (m&7)).
__device__ __forceinline__ void stage64(ushort* __restrict__ lds, const ushort* __restrict__ src,
                                        int row0, int k0, int ld) {
    int t = threadIdx.x;
    int g = t & 7, r = t >> 3;
#pragma unroll
    for (int i = 0; i < 2; ++i, r += 32) {
        uint4 v = *(const uint4*)(src + (row0 + r) * ld + k0 + g * 8);
        *(uint4*)((char*)lds + r * 128 + ((g ^ (r & 7)) << 4)) = v;
    }
}

// stage 64x64 from fp32 source with on-the-fly hi/lo split (256 thr)
__device__ __forceinline__ void stage64_f32(ushort* __restrict__ ldsh, ushort* __restrict__ ldsl,
                                            const float* __restrict__ src, int row0, int k0, int ld) {
    int t = threadIdx.x;
    int g = t & 15, r = t >> 4;
#pragma unroll
    for (int i = 0; i < 4; ++i, r += 16) {
        float4 v = *(const float4*)(src + (row0 + r) * ld + k0 + g * 4);
        ushort h0 = bf16rn(v.x), h1 = bf16rn(v.y), h2 = bf16rn(v.z), h3 = bf16rn(v.w);
        ushort e0 = bf16rn(v.x - bf2f(h0)), e1 = bf16rn(v.y - bf2f(h1));
        ushort e2 = bf16rn(v.z - bf2f(h2)), e3 = bf16rn(v.w - bf2f(h3));
        int byte = r * 128 + ((((g >> 1) ^ (r & 7)) << 4) | ((g & 1) << 3));
        ushort4 hv = {h0, h1, h2, h3}, lv = {e0, e1, e2, e3};
        *(ushort4*)((char*)ldsh + byte) = hv;
        *(ushort4*)((char*)ldsl + byte) = lv;
    }
}

// read one A/B fragment: lane holds row rbase+(l&15), 8 bf16 at k = ks*32+(l>>4)*8
__device__ __forceinline__ bf16x8 frag64(const ushort* __restrict__ lds, int rbase, int ks) {
    int l = threadIdx.x & 63;
    int r = rbase + (l & 15);
    int slot = (ks * 4 + (l >> 4)) ^ (r & 7);
    return *(const bf16x8*)((const char*)lds + r * 128 + slot * 16);
}

__device__ __forceinline__ void mac3(f32x4& acc, bf16x8 ah, bf16x8 al, bf16x8 bh, bf16x8 bl) {
    acc = MFMA16(ah, bh, acc);
    acc = MFMA16(ah, bl, acc);
    acc = MFMA16(al, bh, acc);
}

// 4-wave 64x64 mfma over one staged k-tile (256-thr kernels)
__device__ __forceinline__ void mfma_tile(const ushort* Ah, const ushort* Al,
                                          const ushort* Bh, const ushort* Bl,
                                          int wm, int wn, f32x4 acc[2][2]) {
#pragma unroll
    for (int ks = 0; ks < 2; ++ks) {
        bf16x8 ah[2], al[2], bh[2], bl[2];
        ah[0] = frag64(Ah, wm, ks);      ah[1] = frag64(Ah, wm + 16, ks);
        al[0] = frag64(Al, wm, ks);      al[1] = frag64(Al, wm + 16, ks);
        bh[0] = frag64(Bh, wn, ks);      bh[1] = frag64(Bh, wn + 16, ks);
        bl[0] = frag64(Bl, wn, ks);      bl[1] = frag64(Bl, wn + 16, ks);
#pragma unroll
        for (int mi = 0; mi < 2; ++mi)
#pragma unroll
            for (int ni = 0; ni < 2; ++ni)
                mac3(acc[mi][ni], ah[mi], al[mi], bh[ni], bl[ni]);
    }
}

// full TN GEMM over nkt 64-wide k-tiles; 4 waves, 64x64 output tile, 32 KB LDS
__device__ __forceinline__ void gemm_core(const ushort* Ahi, const ushort* Alo, int arow0, int lda, int k0a,
                                          const ushort* Bhi, const ushort* Blo, int brow0, int ldb, int k0b,
                                          int nkt, ushort* lds, f32x4 acc[2][2]) {
    ushort* Ah = lds; ushort* Al = lds + 4096; ushort* Bh = lds + 8192; ushort* Bl = lds + 12288;
    int w = threadIdx.x >> 6;
    int wm = (w >> 1) * 32, wn = (w & 1) * 32;
    for (int t = 0; t < nkt; ++t) {
        stage64(Ah, Ahi, arow0, k0a + t * 64, lda);
        stage64(Al, Alo, arow0, k0a + t * 64, lda);
        stage64(Bh, Bhi, brow0, k0b + t * 64, ldb);
        stage64(Bl, Blo, brow0, k0b + t * 64, ldb);
        __syncthreads();
        mfma_tile(Ah, Al, Bh, Bl, wm, wn, acc);
        __syncthreads();
    }
}

__device__ __forceinline__ void ep_hilo(ushort* Dh, ushort* Dl, int ld, int row0, int col0, f32x4 acc[2][2]) {
    int l = threadIdx.x & 63, w = threadIdx.x >> 6;
    int wm = (w >> 1) * 32, wn = (w & 1) * 32;
#pragma unroll
    for (int mi = 0; mi < 2; ++mi)
#pragma unroll
        for (int ni = 0; ni < 2; ++ni)
#pragma unroll
            for (int r = 0; r < 4; ++r) {
                float x = acc[mi][ni][r];
                int idx = (row0 + wm + mi * 16 + (l >> 4) * 4 + r) * ld + col0 + wn + ni * 16 + (l & 15);
                ushort h = bf16rn(x);
                Dh[idx] = h;
                Dl[idx] = bf16rn(x - bf2f(h));
            }
}

__device__ __forceinline__ void ep_f32(float* D, int ld, int row0, int col0, f32x4 acc[2][2]) {
    int l = threadIdx.x & 63, w = threadIdx.x >> 6;
    int wm = (w >> 1) * 32, wn = (w & 1) * 32;
#pragma unroll
    for (int mi = 0; mi < 2; ++mi)
#pragma unroll
        for (int ni = 0; ni < 2; ++ni)
#pragma unroll
            for (int r = 0; r < 4; ++r)
                D[(row0 + wm + mi * 16 + (l >> 4) * 4 + r) * ld + col0 + wn + ni * 16 + (l & 15)] = acc[mi][ni][r];
}

// transpose+split a 64x64 fp32 tile: src[m*srcStride + j] -> dst[j*NC + m] (hi/lo)
__device__ __forceinline__ void tsplit(uint (*lds)[65], const float* __restrict__ src, int srcStride,
                                       ushort* __restrict__ DH, ushort* __restrict__ DL) {
    int t = threadIdx.x;
    int r = t >> 4, g = t & 15;
#pragma unroll
    for (int i = 0; i < 4; ++i) {
        int m = r + i * 16;
        float4 v = *(const float4*)(src + m * srcStride + g * 4);
        ushort h;
        h = bf16rn(v.x); lds[g * 4 + 0][m] = h | ((uint)bf16rn(v.x - bf2f(h)) << 16);
        h = bf16rn(v.y); lds[g * 4 + 1][m] = h | ((uint)bf16rn(v.y - bf2f(h)) << 16);
        h = bf16rn(v.z); lds[g * 4 + 2][m] = h | ((uint)bf16rn(v.z - bf2f(h)) << 16);
        h = bf16rn(v.w); lds[g * 4 + 3][m] = h | ((uint)bf16rn(v.w - bf2f(h)) << 16);
    }
    __syncthreads();
    int j = t >> 3, q = t & 7;
#pragma unroll
    for (int i = 0; i < 2; ++i) {
        int jj = j + i * 32;
        uint a0 = lds[jj][q * 8 + 0], a1 = lds[jj][q * 8 + 1], a2 = lds[jj][q * 8 + 2], a3 = lds[jj][q * 8 + 3];
        uint a4 = lds[jj][q * 8 + 4], a5 = lds[jj][q * 8 + 5], a6 = lds[jj][q * 8 + 6], a7 = lds[jj][q * 8 + 7];
        uint4 hv = {(a0 & 0xffffu) | (a1 << 16), (a2 & 0xffffu) | (a3 << 16),
                    (a4 & 0xffffu) | (a5 << 16), (a6 & 0xffffu) | (a7 << 16)};
        uint4 lv = {(a0 >> 16) | (a1 & 0xffff0000u), (a2 >> 16) | (a3 & 0xffff0000u),
                    (a4 >> 16) | (a5 & 0xffff0000u), (a6 >> 16) | (a7 & 0xffff0000u)};
        *(uint4*)(DH + jj * NC + q * 8) = hv;
        *(uint4*)(DL + jj * NC + q * 8) = lv;
    }
}

// ---- kernels ---------------------------------------------------------------

// merged weight prep: z=0 Wq^T, z=1 Wk^T, z=2 Wo rearrange, z=3 Wv split + zero stats
__global__ __launch_bounds__(256) void k_prep(const float* __restrict__ wq, const float* __restrict__ wk,
                                              const float* __restrict__ wv, const float* __restrict__ wo,
                                              ushort* __restrict__ us, float* __restrict__ stats) {
    __shared__ uint lds[64][65];
    int x = blockIdx.x, z = blockIdx.y;
    int t = threadIdx.x;
    if (z == 3) {
        if (x == 0 && t < 64) stats[t] = 0.f;
        int i = (x * 256 + t) * 4;
        float4 v = *(const float4*)(wv + i);
        ushort h0 = bf16rn(v.x), h1 = bf16rn(v.y), h2 = bf16rn(v.z), h3 = bf16rn(v.w);
        ushort e0 = bf16rn(v.x - bf2f(h0)), e1 = bf16rn(v.y - bf2f(h1));
        ushort e2 = bf16rn(v.z - bf2f(h2)), e3 = bf16rn(v.w - bf2f(h3));
        ushort4 hv = {h0, h1, h2, h3}, lv = {e0, e1, e2, e3};
        *(ushort4*)(us + WVH + i) = hv;
        *(ushort4*)(us + WVL + i) = lv;
        return;
    }
    if (x >= 128) return;
    if (z == 2) {
        int h = x >> 4, dt = (x >> 2) & 3, jt = x & 3;
        tsplit(lds, wo + (dt * 64 * 8 + h) * NC + jt * 64, 8 * NC,
               us + WORH + h * 65536 + (jt * 64) * NC + dt * 64,
               us + WORL + h * 65536 + (jt * 64) * NC + dt * 64);
        return;
    }
    int jt = x >> 2, ct = x & 3;
    const float* W = z ? wk : wq;
    int dh = (z ? WKTH : WQTH) + (jt * 64) * NC + ct * 64;
    int dl = (z ? WKTL : WQTL) + (jt * 64) * NC + ct * 64;
    tsplit(lds, W + (ct * 64) * NCH + jt * 64, NCH, us + dh, us + dl);
}

// emb -> Et hi/lo [b][c][n] (transpose + split). grid (128 nt, 4 ct, 2 b)
__global__ __launch_bounds__(256) void k_s0(const float* __restrict__ emb, ushort* __restrict__ us) {
    __shared__ uint lds[64][65];
    int nt = blockIdx.x, ct = blockIdx.y, b = blockIdx.z;
    int t = threadIdx.x;
    const float* E = emb + b * (NN * NC);
    int n0 = nt * 64, c0 = ct * 64;
    int r = t >> 4, g = t & 15;
#pragma unroll
    for (int i = 0; i < 4; ++i) {
        int n = r + i * 16;
        float4 v = *(const float4*)(E + (n0 + n) * NC + c0 + g * 4);
        ushort h;
        h = bf16rn(v.x); lds[g * 4 + 0][n] = h | ((uint)bf16rn(v.x - bf2f(h)) << 16);
        h = bf16rn(v.y); lds[g * 4 + 1][n] = h | ((uint)bf16rn(v.y - bf2f(h)) << 16);
        h = bf16rn(v.z); lds[g * 4 + 2][n] = h | ((uint)bf16rn(v.z - bf2f(h)) << 16);
        h = bf16rn(v.w); lds[g * 4 + 3][n] = h | ((uint)bf16rn(v.w - bf2f(h)) << 16);
    }
    __syncthreads();
    ushort* EH = us + ETH + b * (NC * NN);
    ushort* EL = us + ETL + b * (NC * NN);
    int c = t >> 3, q = t & 7;
#pragma unroll
    for (int i = 0; i < 2; ++i) {
        int cc = c + i * 32;
        uint a0 = lds[cc][q * 8 + 0], a1 = lds[cc][q * 8 + 1], a2 = lds[cc][q * 8 + 2], a3 = lds[cc][q * 8 + 3];
        uint a4 = lds[cc][q * 8 + 4], a5 = lds[cc][q * 8 + 5], a6 = lds[cc][q * 8 + 6], a7 = lds[cc][q * 8 + 7];
        uint4 hv = {(a0 & 0xffffu) | (a1 << 16), (a2 & 0xffffu) | (a3 << 16),
                    (a4 & 0xffffu) | (a5 << 16), (a6 & 0xffffu) | (a7 << 16)};
        uint4 lv = {(a0 >> 16) | (a1 & 0xffff0000u), (a2 >> 16) | (a3 & 0xffff0000u),
                    (a4 >> 16) | (a5 & 0xffff0000u), (a6 >> 16) | (a7 & 0xffff0000u)};
        *(uint4*)(EH + (c0 + cc) * NN + n0 + q * 8) = hv;
        *(uint4*)(EL + (c0 + cc) * NN + n0 + q * 8) = lv;
    }
}

static __device__ const int TI1[10] = {0, 0, 0, 0, 1, 1, 1, 2, 2, 3};
static __device__ const int TI2[10] = {0, 1, 2, 3, 1, 2, 3, 2, 3, 3};

// gram split-K partials over Et, triangular tiles. grid (10, 16, 2)
__global__ __launch_bounds__(256) void k_gram(const ushort* __restrict__ us, float* __restrict__ gp) {
    __shared__ ushort lds[16384];
    ushort* Ah = lds; ushort* Al = lds + 4096; ushort* Bh = lds + 8192; ushort* Bl = lds + 12288;
    int tile = blockIdx.x, kc = blockIdx.y, b = blockIdx.z;
    int c1 = TI1[tile] * 64, c2 = TI2[tile] * 64;
    bool diag = (c1 == c2);
    const ushort* eh = us + ETH + b * (NC * NN);
    const ushort* el = us + ETL + b * (NC * NN);
    int w = threadIdx.x >> 6;
    int wm = (w >> 1) * 32, wn = (w & 1) * 32;
    f32x4 acc[2][2] = {{{0.f, 0.f, 0.f, 0.f}, {0.f, 0.f, 0.f, 0.f}},
                       {{0.f, 0.f, 0.f, 0.f}, {0.f, 0.f, 0.f, 0.f}}};
    for (int kb = 0; kb < 8; ++kb) {
        int n0 = kc * 512 + kb * 64;
        stage64(Ah, eh, c1, n0, NN);
        stage64(Al, el, c1, n0, NN);
        if (!diag) { stage64(Bh, eh, c2, n0, NN); stage64(Bl, el, c2, n0, NN); }
        __syncthreads();
        mfma_tile(Ah, Al, diag ? Ah : Bh, diag ? Al : Bl, wm, wn, acc);
        __syncthreads();
    }
    ep_f32(gp + ((b * 16 + kc) * 10 + tile) * 4096, 64, 0, 0, acc);
}

// reduce 16 gram partials per tri tile, split -> G hi/lo, mirror off-diag. grid (10, 2)
__global__ __launch_bounds__(256) void k_s2(const float* __restrict__ gp, ushort* __restrict__ us) {
    __shared__ float T[64][65];
    int tile = blockIdx.x, b = blockIdx.y;
    int c1 = TI1[tile] * 64, c2 = TI2[tile] * 64;
    int t = threadIdx.x;
    const float* src = gp + (b * 160 + tile) * 4096;
    ushort* GH = us + GHH + b * 65536;
    ushort* GL = us + GHL + b * 65536;
    float4 s[4] = {{0.f, 0.f, 0.f, 0.f}, {0.f, 0.f, 0.f, 0.f}, {0.f, 0.f, 0.f, 0.f}, {0.f, 0.f, 0.f, 0.f}};
    for (int kc = 0; kc < 16; ++kc) {
        const float4* p = (const float4*)(src + kc * 40960);
#pragma unroll
        for (int k2 = 0; k2 < 4; ++k2) {
            float4 v = p[t + k2 * 256];
            s[k2].x += v.x; s[k2].y += v.y; s[k2].z += v.z; s[k2].w += v.w;
        }
    }
#pragma unroll
    for (int k2 = 0; k2 < 4; ++k2) {
        int f = t + k2 * 256;
        int r = f >> 4, c = (f & 15) * 4;
        ushort h0 = bf16rn(s[k2].x), h1 = bf16rn(s[k2].y), h2 = bf16rn(s[k2].z), h3 = bf16rn(s[k2].w);
        ushort e0 = bf16rn(s[k2].x - bf2f(h0)), e1 = bf16rn(s[k2].y - bf2f(h1));
        ushort e2 = bf16rn(s[k2].z - bf2f(h2)), e3 = bf16rn(s[k2].w - bf2f(h3));
        ushort4 hv = {h0, h1, h2, h3}, lv = {e0, e1, e2, e3};
        *(ushort4*)(GH + (c1 + r) * NC + c2 + c) = hv;
        *(ushort4*)(GL + (c1 + r) * NC + c2 + c) = lv;
        T[r][c + 0] = s[k2].x; T[r][c + 1] = s[k2].y; T[r][c + 2] = s[k2].z; T[r][c + 3] = s[k2].w;
    }
    if (c1 != c2) {
        __syncthreads();
#pragma unroll
        for (int k2 = 0; k2 < 4; ++k2) {
            int f = t + k2 * 256;
            int r = f >> 4, c = (f & 15) * 4;
            float a0 = T[c + 0][r], a1 = T[c + 1][r], a2 = T[c + 2][r], a3 = T[c + 3][r];
            ushort h0 = bf16rn(a0), h1 = bf16rn(a1), h2 = bf16rn(a2), h3 = bf16rn(a3);
            ushort e0 = bf16rn(a0 - bf2f(h0)), e1 = bf16rn(a1 - bf2f(h1));
            ushort e2 = bf16rn(a2 - bf2f(h2)), e3 = bf16rn(a3 - bf2f(h3));
            ushort4 hv = {h0, h1, h2, h3}, lv = {e0, e1, e2, e3};
            *(ushort4*)(GH + (c2 + r) * NC + c1 + c) = hv;
            *(ushort4*)(GL + (c2 + r) * NC + c1 + c) = lv;
        }
    }
}

// T1 = Wq^T G. grid (32 mt, 4 nt, 2 b)
__global__ __launch_bounds__(256) void k_t1(ushort* __restrict__ us) {
    __shared__ ushort lds[16384];
    int mt = blockIdx.x, nt = blockIdx.y, b = blockIdx.z;
    f32x4 acc[2][2] = {{{0.f, 0.f, 0.f, 0.f}, {0.f, 0.f, 0.f, 0.f}},
                       {{0.f, 0.f, 0.f, 0.f}, {0.f, 0.f, 0.f, 0.f}}};
    gemm_core(us + WQTH, us + WQTL, mt * 64, NC, 0,
              us + GHH + b * 65536, us + GHL + b * 65536, nt * 64, NC, 0, 4, lds, acc);
    ep_hilo(us + T1H + b * 524288, us + T1L + b * 524288, NC, mt * 64, nt * 64, acc);
}

// attn = T1 @ Wk (per head) + variance stats. grid (16 tiles, 16 bh)
__global__ __launch_bounds__(256) void k_attn(ushort* __restrict__ us, float* __restrict__ attn,
                                              float* __restrict__ stats) {
    __shared__ ushort lds[16384];
    int tile = blockIdx.x, bh = blockIdx.y;
    int b = bh >> 3, h = bh & 7;
    int row0 = (tile >> 2) * 64, col0 = (tile & 3) * 64;
    f32x4 acc[2][2] = {{{0.f, 0.f, 0.f, 0.f}, {0.f, 0.f, 0.f, 0.f}},
                       {{0.f, 0.f, 0.f, 0.f}, {0.f, 0.f, 0.f, 0.f}}};
    gemm_core(us + T1H + b * 524288, us + T1L + b * 524288, h * 256 + row0, NC, 0,
              us + WKTH, us + WKTL, h * 256 + col0, NC, 0, 4, lds, acc);
    float* D = attn + bh * 65536;
    int l = threadIdx.x & 63, w = threadIdx.x >> 6;
    int wm = (w >> 1) * 32, wn = (w & 1) * 32;
    float lsum = 0.f, lss = 0.f;
#pragma unroll
    for (int mi = 0; mi < 2; ++mi)
#pragma unroll
        for (int ni = 0; ni < 2; ++ni)
#pragma unroll
            for (int r = 0; r < 4; ++r) {
                float x = acc[mi][ni][r];
                D[(row0 + wm + mi * 16 + (l >> 4) * 4 + r) * NC + col0 + wn + ni * 16 + (l & 15)] = x;
                lsum += x; lss += x * x;
            }
#pragma unroll
    for (int o = 32; o > 0; o >>= 1) { lsum += __shfl_xor(lsum, o); lss += __shfl_xor(lss, o); }
    if (l == 0) { atomicAdd(&stats[bh * 2], lsum); atomicAdd(&stats[bh * 2 + 1], lss); }
}

// fused instnorm-scale + softmax, write hi/lo. grid (16 bh, 4 rb)
__global__ __launch_bounds__(256) void k_sm(const float* __restrict__ attn, const float* __restrict__ stats,
                                            ushort* __restrict__ us) {
    int bh = blockIdx.x, rb = blockIdx.y;
    float mean = stats[bh * 2] * (1.f / 65536.f);
    float var = stats[bh * 2 + 1] * (1.f / 65536.f) - mean * mean;
    float rs = rsqrtf(var + EPS);
    int w = threadIdx.x >> 6, l = threadIdx.x & 63;
    const float* src = attn + bh * 65536;
    ushort* dh = us + SMH + bh * 65536;
    ushort* dl = us + SML + bh * 65536;
    for (int rr = 0; rr < 16; ++rr) {
        int row = rb * 64 + w * 16 + rr;
        float4 v = *(const float4*)(src + row * 256 + l * 4);
        v.x *= rs; v.y *= rs; v.z *= rs; v.w *= rs;
        float mx = fmaxf(fmaxf(v.x, v.y), fmaxf(v.z, v.w));
#pragma unroll
        for (int o = 32; o > 0; o >>= 1) mx = fmaxf(mx, __shfl_xor(mx, o));
        float e0 = __expf(v.x - mx), e1 = __expf(v.y - mx), e2 = __expf(v.z - mx), e3 = __expf(v.w - mx);
        float se = e0 + e1 + e2 + e3;
#pragma unroll
        for (int o = 32; o > 0; o >>= 1) se += __shfl_xor(se, o);
        float inv = 1.f / se;
        e0 *= inv; e1 *= inv; e2 *= inv; e3 *= inv;
        ushort h0 = bf16rn(e0), h1 = bf16rn(e1), h2 = bf16rn(e2), h3 = bf16rn(e3);
        ushort f0 = bf16rn(e0 - bf2f(h0)), f1 = bf16rn(e1 - bf2f(h1));
        ushort f2 = bf16rn(e2 - bf2f(h2)), f3 = bf16rn(e3 - bf2f(h3));
        ushort4 hv = {h0, h1, h2, h3}, lv = {f0, f1, f2, f3};
        *(ushort4*)(dh + row * 256 + l * 4) = hv;
        *(ushort4*)(dl + row * 256 + l * 4) = lv;
    }
}

// M[c][d] = sum_e Wv[c][h*256+e] SM[d][e]. grid (16 tiles, 16 bh). M overwrites T1.
__global__ __launch_bounds__(256) void k_m(ushort* __restrict__ us) {
    __shared__ ushort lds[16384];
    int tile = blockIdx.x, bh = blockIdx.y;
    int h = bh & 7;
    int c0 = (tile >> 2) * 64, d0 = (tile & 3) * 64;
    f32x4 acc[2][2] = {{{0.f, 0.f, 0.f, 0.f}, {0.f, 0.f, 0.f, 0.f}},
                       {{0.f, 0.f, 0.f, 0.f}, {0.f, 0.f, 0.f, 0.f}}};
    gemm_core(us + WVH, us + WVL, c0, NCH, h * 256,
              us + SMH + bh * 65536, us + SML + bh * 65536, d0, NC, 0, 4, lds, acc);
    ep_hilo(us + T1H + bh * 65536, us + T1L + bh * 65536, NC, c0, d0, acc);
}

// Ptp[bh][j][c] = sum_d Wor[h][j][d] M[bh][c][d]. grid (16 tiles, 16 bh)
__global__ __launch_bounds__(256) void k_pt(ushort* __restrict__ us, float* __restrict__ ptp) {
    __shared__ ushort lds[16384];
    int tile = blockIdx.x, bh = blockIdx.y;
    int h = bh & 7;
    int j0 = (tile >> 2) * 64, c0 = (tile & 3) * 64;
    f32x4 acc[2][2] = {{{0.f, 0.f, 0.f, 0.f}, {0.f, 0.f, 0.f, 0.f}},
                       {{0.f, 0.f, 0.f, 0.f}, {0.f, 0.f, 0.f, 0.f}}};
    gemm_core(us + WORH + h * 65536, us + WORL + h * 65536, j0, NC, 0,
              us + T1H + bh * 65536, us + T1L + bh * 65536, c0, NC, 0, 4, lds, acc);
    ep_f32(ptp + bh * 65536, NC, j0, c0, acc);
}

// Pt[b] = sum_h Ptp[b*8+h], split -> hi/lo. grid (64, 2)
__global__ __launch_bounds__(256) void k_s4(const float* __restrict__ ptp, ushort* __restrict__ us) {
    int b = blockIdx.y;
    int i = (blockIdx.x * 256 + threadIdx.x) * 4;
    const float* src = ptp + b * 8 * 65536 + i;
    float4 s = {0.f, 0.f, 0.f, 0.f};
#pragma unroll
    for (int h = 0; h < 8; ++h) {
        float4 v = *(const float4*)(src + h * 65536);
        s.x += v.x; s.y += v.y; s.z += v.z; s.w += v.w;
    }
    ushort h0 = bf16rn(s.x), h1 = bf16rn(s.y), h2 = bf16rn(s.z), h3 = bf16rn(s.w);
    ushort e0 = bf16rn(s.x - bf2f(h0)), e1 = bf16rn(s.y - bf2f(h1));
    ushort e2 = bf16rn(s.z - bf2f(h2)), e3 = bf16rn(s.w - bf2f(h3));
    ushort4 hv = {h0, h1, h2, h3}, lv = {e0, e1, e2, e3};
    *(ushort4*)(us + PTH + b * 65536 + i) = hv;
    *(ushort4*)(us + PTL + b * 65536 + i) = lv;
}

// out = emb @ Pt^T. grid (128 nt, 4 jt, 2 b). A split on the fly from fp32.
__global__ __launch_bounds__(256) void k_out(const float* __restrict__ emb, const ushort* __restrict__ us,
                                             float* __restrict__ out) {
    __shared__ ushort lds[16384];
    ushort* Ah = lds; ushort* Al = lds + 4096; ushort* Bh = lds + 8192; ushort* Bl = lds + 12288;
    int nt = blockIdx.x, jt = blockIdx.y, b = blockIdx.z;
    const float* E = emb + b * (NN * NC);
    const ushort* PH = us + PTH + b * 65536;
    const ushort* PL = us + PTL + b * 65536;
    int w = threadIdx.x >> 6;
    int wm = (w >> 1) * 32, wn = (w & 1) * 32;
    f32x4 acc[2][2] = {{{0.f, 0.f, 0.f, 0.f}, {0.f, 0.f, 0.f, 0.f}},
                       {{0.f, 0.f, 0.f, 0.f}, {0.f, 0.f, 0.f, 0.f}}};
    for (int t = 0; t < 4; ++t) {
        stage64_f32(Ah, Al, E, nt * 64, t * 64, NC);
        stage64(Bh, PH, jt * 64, t * 64, NC);
        stage64(Bl, PL, jt * 64, t * 64, NC);
        __syncthreads();
        mfma_tile(Ah, Al, Bh, Bl, wm, wn, acc);
        __syncthreads();
    }
    ep_f32(out + b * (NN * NC), NC, nt * 64, jt * 64, acc);
}

// ---------------------------------------------------------------------------

extern "C" void kernel_launch(void* const* d_in, const int* in_sizes, int n_in,
                              void* d_out, int out_size, void* d_ws, size_t ws_size,
                              hipStream_t stream) {
    const float* emb = (const float*)d_in[0];
    const float* Wq  = (const float*)d_in[1];
    const float* Wk  = (const float*)d_in[2];
    const float* Wv  = (const float*)d_in[3];
    const float* Wo  = (const float*)d_in[4];
    float* out = (float*)d_out;
    float* ws  = (float*)d_ws;

    float* Gp    = ws;                 // [2][16][10][4096]
    float* attn  = ws;                 // alias (Gp dead after k_s2)
    float* Ptp   = ws + 1310720;       // [16][65536]
    float* stats = ws + 2359296;       // 64 floats
    ushort* us   = (ushort*)(ws + 2359360);

    k_prep<<<dim3(512, 4),     dim3(256), 0, stream>>>(Wq, Wk, Wv, Wo, us, stats);
    k_s0  <<<dim3(128, 4, NB), dim3(256), 0, stream>>>(emb, us);
    k_gram<<<dim3(10, 16, NB), dim3(256), 0, stream>>>(us, Gp);
    k_s2  <<<dim3(10, NB),     dim3(256), 0, stream>>>(Gp, us);
    k_t1  <<<dim3(32, 4, NB),  dim3(256), 0, stream>>>(us);
    k_attn<<<dim3(16, 16),     dim3(256), 0, stream>>>(us, attn, stats);
    k_sm  <<<dim3(16, 4),      dim3(256), 0, stream>>>(attn, stats, us);
    k_m   <<<dim3(16, 16),     dim3(256), 0, stream>>>(us);
    k_pt  <<<dim3(16, 16),     dim3(256), 0, stream>>>(us, Ptp);
    k_s4  <<<dim3(64, NB),     dim3(256), 0, stream>>>(Ptp, us);
    k_out <<<dim3(128, 4, NB), dim3(256), 0, stream>>>(emb, us, out);
}